// Round 2
// baseline (579.034 us; speedup 1.0000x reference)
//
#include <hip/hip_runtime.h>
#include <math.h>

#define F_IN 128
#define HID  32

#define NPB   256      // nodes per scan chunk
#define MAXNB 1024     // max chunks supported by the one-block scan

__device__ __forceinline__ void fma4(float4& a, float s, const float4& w) {
    a.x = fmaf(s, w.x, a.x);
    a.y = fmaf(s, w.y, a.y);
    a.z = fmaf(s, w.z, a.z);
    a.w = fmaf(s, w.w, a.w);
}

// ================= direct CSR build =================
// deg -> hierarchical scan -> atomic scatter. Every kernel fully
// grid-parallel; no binned partition (its scatter-run coalescing vs
// occupancy tension cost ~120us in the old build).

__global__ __launch_bounds__(256) void k_deg(const int* __restrict__ dst,
                                             int* __restrict__ deg, int e) {
    int i = blockIdx.x * 256 + threadIdx.x;
    int stride = gridDim.x * 256;
    for (; i < e; i += stride)
        atomicAdd(&deg[dst[i]], 1);
}

__global__ __launch_bounds__(256) void k_chunksum(const int* __restrict__ deg,
                                                  int* __restrict__ bin_hist, int n) {
    __shared__ int sh[256];
    int b = blockIdx.x, t = threadIdx.x;
    int node = b * 256 + t;
    sh[t] = (node < n) ? deg[node] : 0;
    __syncthreads();
    for (int off = 128; off > 0; off >>= 1) {
        if (t < off) sh[t] += sh[t + off];
        __syncthreads();
    }
    if (t == 0) bin_hist[b] = sh[0];
}

__global__ __launch_bounds__(1024) void k_bscan(const int* __restrict__ bin_hist,
                                                int* __restrict__ bin_off,
                                                int* __restrict__ offsets,
                                                int nbuckets, int n, int e) {
    __shared__ int sh[MAXNB];
    int t = threadIdx.x;
    int v = (t < nbuckets) ? bin_hist[t] : 0;
    sh[t] = v; __syncthreads();
    for (int off = 1; off < MAXNB; off <<= 1) {
        int a = (t >= off) ? sh[t - off] : 0;
        __syncthreads();
        sh[t] += a;
        __syncthreads();
    }
    int excl = sh[t] - v;
    if (t < nbuckets) bin_off[t] = excl;
    if (t == 0) { bin_off[nbuckets] = e; offsets[n] = e; }
}

__global__ __launch_bounds__(256) void k_offsets(const int* __restrict__ deg,
                                                 const int* __restrict__ bin_off,
                                                 int* __restrict__ offsets,
                                                 int* __restrict__ cur,
                                                 float* __restrict__ dis, int n) {
    __shared__ int sh[256];
    int b = blockIdx.x, t = threadIdx.x;
    int node = b * 256 + t;
    int v = (node < n) ? deg[node] : 0;
    sh[t] = v; __syncthreads();
    for (int off = 1; off < 256; off <<= 1) {
        int a = (t >= off) ? sh[t - off] : 0;
        __syncthreads();
        sh[t] += a;
        __syncthreads();
    }
    int excl = sh[t] - v;
    if (node < n) {
        int o = bin_off[b] + excl;
        offsets[node] = o;
        cur[node] = o;
        dis[node] = rsqrtf((float)(v + 1));
    }
}

__global__ __launch_bounds__(256) void k_scatter(const int* __restrict__ src,
                                                 const int* __restrict__ dst,
                                                 int* __restrict__ cur,
                                                 int* __restrict__ es, int e) {
    int i = blockIdx.x * 256 + threadIdx.x;
    int stride = gridDim.x * 256;
    for (; i < e; i += stride) {
        int d = dst[i];
        int r = atomicAdd(&cur[d], 1);
        es[r] = src[i];
    }
}

// ================= transforms =================

// m=4 (128 nodes/block): amortizes the W ds_read_b128 traffic (LDS pipe
// is CU-shared; it was the binding pipe at m=2).
__global__ __launch_bounds__(256) void k_gemm1(const float* __restrict__ x,
                                               const float* __restrict__ W,
                                               const float* __restrict__ dis,
                                               float* __restrict__ u, int n) {
    __shared__ float Ws[F_IN * HID];
    int tid = threadIdx.x;
    for (int i = tid; i < F_IN * HID; i += 256) Ws[i] = W[i];
    int node0 = blockIdx.x * 128;
    int cg = tid & 7, gq = tid >> 3;
    int row[4];
#pragma unroll
    for (int m = 0; m < 4; ++m) {
        int node = node0 + gq + 32 * m;
        row[m] = (node < n) ? node : 0;
    }
    const float4* x4 = (const float4*)x;
    float4 acc[4];
#pragma unroll
    for (int m = 0; m < 4; ++m) acc[m] = make_float4(0.f, 0.f, 0.f, 0.f);
    __syncthreads();
#pragma unroll 4
    for (int ks = 0; ks < 32; ++ks) {
        float4 xv[4];
#pragma unroll
        for (int m = 0; m < 4; ++m) xv[m] = x4[(size_t)row[m] * 32 + ks];
        float4 w0 = *(const float4*)&Ws[(ks * 4 + 0) * HID + cg * 4];
        float4 w1 = *(const float4*)&Ws[(ks * 4 + 1) * HID + cg * 4];
        float4 w2 = *(const float4*)&Ws[(ks * 4 + 2) * HID + cg * 4];
        float4 w3 = *(const float4*)&Ws[(ks * 4 + 3) * HID + cg * 4];
#pragma unroll
        for (int m = 0; m < 4; ++m) {
            fma4(acc[m], xv[m].x, w0);
            fma4(acc[m], xv[m].y, w1);
            fma4(acc[m], xv[m].z, w2);
            fma4(acc[m], xv[m].w, w3);
        }
    }
#pragma unroll
    for (int m = 0; m < 4; ++m) {
        int node = node0 + gq + 32 * m;
        if (node < n) {
            float ds = dis[node];
            float4 r;
            r.x = acc[m].x * ds; r.y = acc[m].y * ds;
            r.z = acc[m].z * ds; r.w = acc[m].w * ds;
            *(float4*)&u[(size_t)node * HID + cg * 4] = r;
        }
    }
}

__global__ __launch_bounds__(256) void k_gemm2(const float* __restrict__ h,
                                               const float* __restrict__ W,
                                               const float* __restrict__ dis,
                                               float* __restrict__ u, int n) {
    __shared__ float Ws[HID * HID];
    int tid = threadIdx.x;
    for (int i = tid; i < HID * HID; i += 256) Ws[i] = W[i];
    int node0 = blockIdx.x * 128;
    int cg = tid & 7, gq = tid >> 3;
    int row[4];
#pragma unroll
    for (int m = 0; m < 4; ++m) {
        int node = node0 + gq + 32 * m;
        row[m] = (node < n) ? node : 0;
    }
    const float4* h4 = (const float4*)h;
    float4 acc[4];
#pragma unroll
    for (int m = 0; m < 4; ++m) acc[m] = make_float4(0.f, 0.f, 0.f, 0.f);
    __syncthreads();
#pragma unroll 4
    for (int ks = 0; ks < 8; ++ks) {
        float4 xv[4];
#pragma unroll
        for (int m = 0; m < 4; ++m) xv[m] = h4[(size_t)row[m] * 8 + ks];
        float4 w0 = *(const float4*)&Ws[(ks * 4 + 0) * HID + cg * 4];
        float4 w1 = *(const float4*)&Ws[(ks * 4 + 1) * HID + cg * 4];
        float4 w2 = *(const float4*)&Ws[(ks * 4 + 2) * HID + cg * 4];
        float4 w3 = *(const float4*)&Ws[(ks * 4 + 3) * HID + cg * 4];
#pragma unroll
        for (int m = 0; m < 4; ++m) {
            fma4(acc[m], xv[m].x, w0);
            fma4(acc[m], xv[m].y, w1);
            fma4(acc[m], xv[m].z, w2);
            fma4(acc[m], xv[m].w, w3);
        }
    }
#pragma unroll
    for (int m = 0; m < 4; ++m) {
        int node = node0 + gq + 32 * m;
        if (node < n) {
            float ds = dis[node];
            float4 r;
            r.x = acc[m].x * ds; r.y = acc[m].y * ds;
            r.z = acc[m].z * ds; r.w = acc[m].w * ds;
            *(float4*)&u[(size_t)node * HID + cg * 4] = r;
        }
    }
}

// ================= gather aggregation =================

__global__ __launch_bounds__(256) void k_gather32(const float4* __restrict__ u4,
                                                  const int* __restrict__ es,
                                                  const int* __restrict__ offsets,
                                                  const float* __restrict__ dis,
                                                  const float* __restrict__ b,
                                                  float4* __restrict__ h4, int n) {
    int t = blockIdx.x * 256 + threadIdx.x;
    int node = t >> 3, q = t & 7;
    if (node >= n) return;
    int s0 = offsets[node];
    int s1 = offsets[node + 1];
    float4 acc = u4[(size_t)node * 8 + q];   // self-loop
    int ei = s0;
    for (; ei + 4 <= s1; ei += 4) {
        int e0 = es[ei], e1 = es[ei + 1], e2 = es[ei + 2], e3 = es[ei + 3];
        float4 v0 = u4[(size_t)e0 * 8 + q];
        float4 v1 = u4[(size_t)e1 * 8 + q];
        float4 v2 = u4[(size_t)e2 * 8 + q];
        float4 v3 = u4[(size_t)e3 * 8 + q];
        acc.x += (v0.x + v1.x) + (v2.x + v3.x);
        acc.y += (v0.y + v1.y) + (v2.y + v3.y);
        acc.z += (v0.z + v1.z) + (v2.z + v3.z);
        acc.w += (v0.w + v1.w) + (v2.w + v3.w);
    }
    for (; ei < s1; ++ei) {
        int s = es[ei];
        float4 v = u4[(size_t)s * 8 + q];
        acc.x += v.x; acc.y += v.y; acc.z += v.z; acc.w += v.w;
    }
    float ds = dis[node];
    float4 r;
    r.x = fmaxf(fmaf(ds, acc.x, b[q * 4 + 0]), 0.0f);
    r.y = fmaxf(fmaf(ds, acc.y, b[q * 4 + 1]), 0.0f);
    r.z = fmaxf(fmaf(ds, acc.z, b[q * 4 + 2]), 0.0f);
    r.w = fmaxf(fmaf(ds, acc.w, b[q * 4 + 3]), 0.0f);
    h4[(size_t)node * 8 + q] = r;
}

__global__ __launch_bounds__(256) void k_gather32_dot(const float4* __restrict__ u4,
                                                      const int* __restrict__ es,
                                                      const int* __restrict__ offsets,
                                                      const float* __restrict__ dis,
                                                      const float* __restrict__ b,
                                                      const float* __restrict__ W3,
                                                      float* __restrict__ s, int n) {
    int t = blockIdx.x * 256 + threadIdx.x;
    int node = t >> 3, q = t & 7;
    if (node >= n) return;
    int s0 = offsets[node];
    int s1 = offsets[node + 1];
    float4 acc = u4[(size_t)node * 8 + q];
    int ei = s0;
    for (; ei + 4 <= s1; ei += 4) {
        int e0 = es[ei], e1 = es[ei + 1], e2 = es[ei + 2], e3 = es[ei + 3];
        float4 v0 = u4[(size_t)e0 * 8 + q];
        float4 v1 = u4[(size_t)e1 * 8 + q];
        float4 v2 = u4[(size_t)e2 * 8 + q];
        float4 v3 = u4[(size_t)e3 * 8 + q];
        acc.x += (v0.x + v1.x) + (v2.x + v3.x);
        acc.y += (v0.y + v1.y) + (v2.y + v3.y);
        acc.z += (v0.z + v1.z) + (v2.z + v3.z);
        acc.w += (v0.w + v1.w) + (v2.w + v3.w);
    }
    for (; ei < s1; ++ei) {
        int sc = es[ei];
        float4 v = u4[(size_t)sc * 8 + q];
        acc.x += v.x; acc.y += v.y; acc.z += v.z; acc.w += v.w;
    }
    float ds = dis[node];
    float4 r;
    r.x = fmaxf(fmaf(ds, acc.x, b[q * 4 + 0]), 0.0f);
    r.y = fmaxf(fmaf(ds, acc.y, b[q * 4 + 1]), 0.0f);
    r.z = fmaxf(fmaf(ds, acc.z, b[q * 4 + 2]), 0.0f);
    r.w = fmaxf(fmaf(ds, acc.w, b[q * 4 + 3]), 0.0f);
    float p = r.x * W3[q * 4 + 0] + r.y * W3[q * 4 + 1]
            + r.z * W3[q * 4 + 2] + r.w * W3[q * 4 + 3];
    p += __shfl_down(p, 4, 8);
    p += __shfl_down(p, 2, 8);
    p += __shfl_down(p, 1, 8);
    if (q == 0) s[node] = p * ds;
}

__global__ void k_gather1(const float* __restrict__ sv, const int* __restrict__ es,
                          const int* __restrict__ offsets, const float* __restrict__ dis,
                          const float* __restrict__ b3, float* __restrict__ out, int n) {
    int d = blockIdx.x * 256 + threadIdx.x;
    if (d >= n) return;
    float acc = sv[d];
    int s0 = offsets[d], s1 = offsets[d + 1];
    int ei = s0;
    for (; ei + 4 <= s1; ei += 4) {
        float v0 = sv[es[ei]], v1 = sv[es[ei + 1]];
        float v2 = sv[es[ei + 2]], v3 = sv[es[ei + 3]];
        acc += (v0 + v1) + (v2 + v3);
    }
    for (; ei < s1; ++ei) acc += sv[es[ei]];
    float z = dis[d] * acc + b3[0];
    out[d] = 1.0f / (1.0f + expf(-z));
}

// ================= launch =================

extern "C" void kernel_launch(void* const* d_in, const int* in_sizes, int n_in,
                              void* d_out, int out_size, void* d_ws, size_t ws_size,
                              hipStream_t stream) {
    const float* x  = (const float*)d_in[0];
    const int*   ei = (const int*)d_in[1];
    const float* W1 = (const float*)d_in[2];
    const float* b1 = (const float*)d_in[3];
    const float* W2 = (const float*)d_in[4];
    const float* b2 = (const float*)d_in[5];
    const float* W3 = (const float*)d_in[6];
    const float* b3 = (const float*)d_in[7];
    float* out = (float*)d_out;

    int n = out_size;             // 150000
    int e = in_sizes[1] / 2;      // 2400000
    const int* src = ei;
    const int* dst = ei + e;

    int nbuckets = (n + NPB - 1) / NPB;   // 586

    float* A        = (float*)d_ws;                 // n*32 f
    float* B        = A + (size_t)n * HID;          // n*32 f
    float* dis      = B + (size_t)n * HID;          // n f
    float* Cs       = dis + n;                      // n f
    int*   offsets  = (int*)(Cs + n);               // n+1 i
    int*   es       = offsets + (n + 1);            // e i
    int*   deg      = es + e;                       // n i
    int*   cur      = deg + n;                      // n i
    int*   bin_hist = cur + n;                      // nbuckets i
    int*   bin_off  = bin_hist + nbuckets;          // nbuckets+1 i

    dim3 blk(256);
    int gN    = (n + 255) / 256;
    int gN8   = (n * 8 + 255) / 256;
    int g128  = (n + 127) / 128;       // 1172
    int gE    = 2048;                  // grid-stride over edges

    // ---- CSR build: deg -> scan -> scatter ----
    hipMemsetAsync(deg, 0, (size_t)n * sizeof(int), stream);
    k_deg     <<<gE, blk, 0, stream>>>(dst, deg, e);
    k_chunksum<<<nbuckets, blk, 0, stream>>>(deg, bin_hist, n);
    k_bscan   <<<1, 1024, 0, stream>>>(bin_hist, bin_off, offsets, nbuckets, n, e);
    k_offsets <<<nbuckets, blk, 0, stream>>>(deg, bin_off, offsets, cur, dis, n);
    k_scatter <<<gE, blk, 0, stream>>>(src, dst, cur, es, e);

    // ---- layer 1 ----
    k_gemm1   <<<g128, blk, 0, stream>>>(x, W1, dis, A, n);
    k_gather32<<<gN8, blk, 0, stream>>>((const float4*)A, es, offsets, dis, b1, (float4*)B, n);

    // ---- layer 2 (+ fused layer-3 transform) ----
    k_gemm2       <<<g128, blk, 0, stream>>>(B, W2, dis, A, n);
    k_gather32_dot<<<gN8, blk, 0, stream>>>((const float4*)A, es, offsets, dis, b2, W3, Cs, n);

    // ---- layer 3 aggregation ----
    k_gather1<<<gN, blk, 0, stream>>>(Cs, es, offsets, dis, b3, out, n);
}

// Round 3
// 347.090 us; speedup vs baseline: 1.6683x; 1.6683x over previous
//
#include <hip/hip_runtime.h>
#include <math.h>

#define F_IN 128
#define HID  32

#define NPB   256      // nodes per bucket (dst >> 8)
#define MAXNB 1024     // max buckets supported by the one-block scan
#define EPB   8192     // edges per block in coarse passes (293 blocks @ 2.4M)
#define BLK_E 1024     // threads per block for coarse passes
#define BLK_C 512      // threads per block for k_bcsr

__device__ __forceinline__ void fma4(float4& a, float s, const float4& w) {
    a.x = fmaf(s, w.x, a.x);
    a.y = fmaf(s, w.y, a.y);
    a.z = fmaf(s, w.z, a.z);
    a.w = fmaf(s, w.w, a.w);
}

// ================= binned CSR build =================
// Round-0 structure restored: block-local binning gives the scatter its
// write locality (runs of ~14 edges into tmp; es writes into a 16KB
// block-owned window). Direct atomic scatter (round 2) cost 64B/write.
// New: int4 edge loads (4 edges/thread/iter) for MLP in the
// latency-bound passes.

__global__ __launch_bounds__(BLK_E) void k_bhist(const int* __restrict__ dst,
                                                 int* __restrict__ bin_hist,
                                                 int e, int nbuckets) {
    __shared__ int h[MAXNB];
    int tid = threadIdx.x;
    for (int i = tid; i < nbuckets; i += BLK_E) h[i] = 0;
    __syncthreads();
    int base = blockIdx.x * EPB;
    if (base + EPB <= e) {
        const int4* d4 = (const int4*)(dst + base);
#pragma unroll
        for (int i = tid; i < EPB / 4; i += BLK_E) {
            int4 v = d4[i];
            atomicAdd(&h[v.x >> 8], 1);
            atomicAdd(&h[v.y >> 8], 1);
            atomicAdd(&h[v.z >> 8], 1);
            atomicAdd(&h[v.w >> 8], 1);
        }
    } else {
        int end = e;
        for (int i = base + tid; i < end; i += BLK_E)
            atomicAdd(&h[dst[i] >> 8], 1);
    }
    __syncthreads();
    for (int i = tid; i < nbuckets; i += BLK_E)
        if (h[i]) atomicAdd(&bin_hist[i], h[i]);
}

__global__ __launch_bounds__(1024) void k_bscan(const int* __restrict__ bin_hist,
                                                int* __restrict__ bin_off,
                                                int* __restrict__ bin_cur,
                                                int* __restrict__ offsets,
                                                int nbuckets, int n, int e) {
    __shared__ int sh[MAXNB];
    int t = threadIdx.x;
    int v = (t < nbuckets) ? bin_hist[t] : 0;
    sh[t] = v; __syncthreads();
    for (int off = 1; off < MAXNB; off <<= 1) {
        int a = (t >= off) ? sh[t - off] : 0;
        __syncthreads();
        sh[t] += a;
        __syncthreads();
    }
    int excl = sh[t] - v;
    if (t < nbuckets) { bin_off[t] = excl; bin_cur[t] = excl; }
    if (t == 0) { bin_off[nbuckets] = e; offsets[n] = e; }
}

__global__ __launch_bounds__(BLK_E) void k_bpart(const int* __restrict__ src,
                                                 const int* __restrict__ dst,
                                                 int* __restrict__ bin_cur,
                                                 unsigned* __restrict__ tmp,
                                                 int e, int nbuckets) {
    __shared__ int h[MAXNB];
    __shared__ int lc[MAXNB];
    int tid = threadIdx.x;
    for (int i = tid; i < nbuckets; i += BLK_E) h[i] = 0;
    __syncthreads();
    int base = blockIdx.x * EPB;
    bool full = (base + EPB <= e);
    if (full) {
        const int4* d4 = (const int4*)(dst + base);
#pragma unroll
        for (int i = tid; i < EPB / 4; i += BLK_E) {
            int4 v = d4[i];
            atomicAdd(&h[v.x >> 8], 1);
            atomicAdd(&h[v.y >> 8], 1);
            atomicAdd(&h[v.z >> 8], 1);
            atomicAdd(&h[v.w >> 8], 1);
        }
    } else {
        for (int i = base + tid; i < e; i += BLK_E)
            atomicAdd(&h[dst[i] >> 8], 1);
    }
    __syncthreads();
    for (int i = tid; i < nbuckets; i += BLK_E) {
        int c = h[i];
        h[i] = c ? atomicAdd(&bin_cur[i], c) : 0;
        lc[i] = 0;
    }
    __syncthreads();
    if (full) {
        const int4* s4 = (const int4*)(src + base);
        const int4* d4 = (const int4*)(dst + base);
#pragma unroll
        for (int i = tid; i < EPB / 4; i += BLK_E) {
            int4 sv = s4[i];
            int4 dv = d4[i];
            int b0 = dv.x >> 8; int r0 = atomicAdd(&lc[b0], 1);
            tmp[h[b0] + r0] = (unsigned)sv.x | ((unsigned)(dv.x & (NPB - 1)) << 18);
            int b1 = dv.y >> 8; int r1 = atomicAdd(&lc[b1], 1);
            tmp[h[b1] + r1] = (unsigned)sv.y | ((unsigned)(dv.y & (NPB - 1)) << 18);
            int b2 = dv.z >> 8; int r2 = atomicAdd(&lc[b2], 1);
            tmp[h[b2] + r2] = (unsigned)sv.z | ((unsigned)(dv.z & (NPB - 1)) << 18);
            int b3 = dv.w >> 8; int r3 = atomicAdd(&lc[b3], 1);
            tmp[h[b3] + r3] = (unsigned)sv.w | ((unsigned)(dv.w & (NPB - 1)) << 18);
        }
    } else {
        for (int i = base + tid; i < e; i += BLK_E) {
            int d = dst[i];
            int b = d >> 8;
            int r = atomicAdd(&lc[b], 1);
            tmp[h[b] + r] = (unsigned)src[i] | ((unsigned)(d & (NPB - 1)) << 18);
        }
    }
}

__global__ __launch_bounds__(BLK_C) void k_bcsr(const unsigned* __restrict__ tmp,
                                                const int* __restrict__ bin_off,
                                                int* __restrict__ es,
                                                int* __restrict__ offsets,
                                                float* __restrict__ dis, int n) {
    __shared__ int cnt[NPB];
    __shared__ int sh[NPB];
    __shared__ int cur[NPB];
    int b = blockIdx.x, t = threadIdx.x;
    if (t < NPB) cnt[t] = 0;
    __syncthreads();
    int s0 = bin_off[b], s1 = bin_off[b + 1];
    for (int i = s0 + t; i < s1; i += BLK_C)
        atomicAdd(&cnt[(tmp[i] >> 18) & (NPB - 1)], 1);
    __syncthreads();
    int v = (t < NPB) ? cnt[t] : 0;
    if (t < NPB) sh[t] = v;
    __syncthreads();
    for (int off = 1; off < NPB; off <<= 1) {
        int a = (t < NPB && t >= off) ? sh[t - off] : 0;
        __syncthreads();
        if (t < NPB) sh[t] += a;
        __syncthreads();
    }
    if (t < NPB) {
        int excl = sh[t] - v;
        int node = b * NPB + t;
        if (node < n) {
            offsets[node] = s0 + excl;
            dis[node] = rsqrtf((float)(v + 1));
        }
        cur[t] = excl;
    }
    __syncthreads();
    for (int i = s0 + t; i < s1; i += BLK_C) {
        unsigned w = tmp[i];
        int dl = (w >> 18) & (NPB - 1);
        int r = atomicAdd(&cur[dl], 1);
        es[s0 + r] = (int)(w & 0x3FFFFu);
    }
}

// ================= transforms =================

// m=4 (128 nodes/block): amortizes the W ds_read_b128 traffic (LDS pipe
// is CU-shared; it was the binding pipe at m=2).
__global__ __launch_bounds__(256) void k_gemm1(const float* __restrict__ x,
                                               const float* __restrict__ W,
                                               const float* __restrict__ dis,
                                               float* __restrict__ u, int n) {
    __shared__ float Ws[F_IN * HID];
    int tid = threadIdx.x;
    for (int i = tid; i < F_IN * HID; i += 256) Ws[i] = W[i];
    int node0 = blockIdx.x * 128;
    int cg = tid & 7, gq = tid >> 3;
    int row[4];
#pragma unroll
    for (int m = 0; m < 4; ++m) {
        int node = node0 + gq + 32 * m;
        row[m] = (node < n) ? node : 0;
    }
    const float4* x4 = (const float4*)x;
    float4 acc[4];
#pragma unroll
    for (int m = 0; m < 4; ++m) acc[m] = make_float4(0.f, 0.f, 0.f, 0.f);
    __syncthreads();
#pragma unroll 4
    for (int ks = 0; ks < 32; ++ks) {
        float4 xv[4];
#pragma unroll
        for (int m = 0; m < 4; ++m) xv[m] = x4[(size_t)row[m] * 32 + ks];
        float4 w0 = *(const float4*)&Ws[(ks * 4 + 0) * HID + cg * 4];
        float4 w1 = *(const float4*)&Ws[(ks * 4 + 1) * HID + cg * 4];
        float4 w2 = *(const float4*)&Ws[(ks * 4 + 2) * HID + cg * 4];
        float4 w3 = *(const float4*)&Ws[(ks * 4 + 3) * HID + cg * 4];
#pragma unroll
        for (int m = 0; m < 4; ++m) {
            fma4(acc[m], xv[m].x, w0);
            fma4(acc[m], xv[m].y, w1);
            fma4(acc[m], xv[m].z, w2);
            fma4(acc[m], xv[m].w, w3);
        }
    }
#pragma unroll
    for (int m = 0; m < 4; ++m) {
        int node = node0 + gq + 32 * m;
        if (node < n) {
            float ds = dis[node];
            float4 r;
            r.x = acc[m].x * ds; r.y = acc[m].y * ds;
            r.z = acc[m].z * ds; r.w = acc[m].w * ds;
            *(float4*)&u[(size_t)node * HID + cg * 4] = r;
        }
    }
}

__global__ __launch_bounds__(256) void k_gemm2(const float* __restrict__ h,
                                               const float* __restrict__ W,
                                               const float* __restrict__ dis,
                                               float* __restrict__ u, int n) {
    __shared__ float Ws[HID * HID];
    int tid = threadIdx.x;
    for (int i = tid; i < HID * HID; i += 256) Ws[i] = W[i];
    int node0 = blockIdx.x * 128;
    int cg = tid & 7, gq = tid >> 3;
    int row[4];
#pragma unroll
    for (int m = 0; m < 4; ++m) {
        int node = node0 + gq + 32 * m;
        row[m] = (node < n) ? node : 0;
    }
    const float4* h4 = (const float4*)h;
    float4 acc[4];
#pragma unroll
    for (int m = 0; m < 4; ++m) acc[m] = make_float4(0.f, 0.f, 0.f, 0.f);
    __syncthreads();
#pragma unroll 4
    for (int ks = 0; ks < 8; ++ks) {
        float4 xv[4];
#pragma unroll
        for (int m = 0; m < 4; ++m) xv[m] = h4[(size_t)row[m] * 8 + ks];
        float4 w0 = *(const float4*)&Ws[(ks * 4 + 0) * HID + cg * 4];
        float4 w1 = *(const float4*)&Ws[(ks * 4 + 1) * HID + cg * 4];
        float4 w2 = *(const float4*)&Ws[(ks * 4 + 2) * HID + cg * 4];
        float4 w3 = *(const float4*)&Ws[(ks * 4 + 3) * HID + cg * 4];
#pragma unroll
        for (int m = 0; m < 4; ++m) {
            fma4(acc[m], xv[m].x, w0);
            fma4(acc[m], xv[m].y, w1);
            fma4(acc[m], xv[m].z, w2);
            fma4(acc[m], xv[m].w, w3);
        }
    }
#pragma unroll
    for (int m = 0; m < 4; ++m) {
        int node = node0 + gq + 32 * m;
        if (node < n) {
            float ds = dis[node];
            float4 r;
            r.x = acc[m].x * ds; r.y = acc[m].y * ds;
            r.z = acc[m].z * ds; r.w = acc[m].w * ds;
            *(float4*)&u[(size_t)node * HID + cg * 4] = r;
        }
    }
}

// ================= gather aggregation =================

__global__ __launch_bounds__(256) void k_gather32(const float4* __restrict__ u4,
                                                  const int* __restrict__ es,
                                                  const int* __restrict__ offsets,
                                                  const float* __restrict__ dis,
                                                  const float* __restrict__ b,
                                                  float4* __restrict__ h4, int n) {
    int t = blockIdx.x * 256 + threadIdx.x;
    int node = t >> 3, q = t & 7;
    if (node >= n) return;
    int s0 = offsets[node];
    int s1 = offsets[node + 1];
    float4 acc = u4[(size_t)node * 8 + q];   // self-loop
    int ei = s0;
    for (; ei + 4 <= s1; ei += 4) {
        int e0 = es[ei], e1 = es[ei + 1], e2 = es[ei + 2], e3 = es[ei + 3];
        float4 v0 = u4[(size_t)e0 * 8 + q];
        float4 v1 = u4[(size_t)e1 * 8 + q];
        float4 v2 = u4[(size_t)e2 * 8 + q];
        float4 v3 = u4[(size_t)e3 * 8 + q];
        acc.x += (v0.x + v1.x) + (v2.x + v3.x);
        acc.y += (v0.y + v1.y) + (v2.y + v3.y);
        acc.z += (v0.z + v1.z) + (v2.z + v3.z);
        acc.w += (v0.w + v1.w) + (v2.w + v3.w);
    }
    for (; ei < s1; ++ei) {
        int s = es[ei];
        float4 v = u4[(size_t)s * 8 + q];
        acc.x += v.x; acc.y += v.y; acc.z += v.z; acc.w += v.w;
    }
    float ds = dis[node];
    float4 r;
    r.x = fmaxf(fmaf(ds, acc.x, b[q * 4 + 0]), 0.0f);
    r.y = fmaxf(fmaf(ds, acc.y, b[q * 4 + 1]), 0.0f);
    r.z = fmaxf(fmaf(ds, acc.z, b[q * 4 + 2]), 0.0f);
    r.w = fmaxf(fmaf(ds, acc.w, b[q * 4 + 3]), 0.0f);
    h4[(size_t)node * 8 + q] = r;
}

__global__ __launch_bounds__(256) void k_gather32_dot(const float4* __restrict__ u4,
                                                      const int* __restrict__ es,
                                                      const int* __restrict__ offsets,
                                                      const float* __restrict__ dis,
                                                      const float* __restrict__ b,
                                                      const float* __restrict__ W3,
                                                      float* __restrict__ s, int n) {
    int t = blockIdx.x * 256 + threadIdx.x;
    int node = t >> 3, q = t & 7;
    if (node >= n) return;
    int s0 = offsets[node];
    int s1 = offsets[node + 1];
    float4 acc = u4[(size_t)node * 8 + q];
    int ei = s0;
    for (; ei + 4 <= s1; ei += 4) {
        int e0 = es[ei], e1 = es[ei + 1], e2 = es[ei + 2], e3 = es[ei + 3];
        float4 v0 = u4[(size_t)e0 * 8 + q];
        float4 v1 = u4[(size_t)e1 * 8 + q];
        float4 v2 = u4[(size_t)e2 * 8 + q];
        float4 v3 = u4[(size_t)e3 * 8 + q];
        acc.x += (v0.x + v1.x) + (v2.x + v3.x);
        acc.y += (v0.y + v1.y) + (v2.y + v3.y);
        acc.z += (v0.z + v1.z) + (v2.z + v3.z);
        acc.w += (v0.w + v1.w) + (v2.w + v3.w);
    }
    for (; ei < s1; ++ei) {
        int sc = es[ei];
        float4 v = u4[(size_t)sc * 8 + q];
        acc.x += v.x; acc.y += v.y; acc.z += v.z; acc.w += v.w;
    }
    float ds = dis[node];
    float4 r;
    r.x = fmaxf(fmaf(ds, acc.x, b[q * 4 + 0]), 0.0f);
    r.y = fmaxf(fmaf(ds, acc.y, b[q * 4 + 1]), 0.0f);
    r.z = fmaxf(fmaf(ds, acc.z, b[q * 4 + 2]), 0.0f);
    r.w = fmaxf(fmaf(ds, acc.w, b[q * 4 + 3]), 0.0f);
    float p = r.x * W3[q * 4 + 0] + r.y * W3[q * 4 + 1]
            + r.z * W3[q * 4 + 2] + r.w * W3[q * 4 + 3];
    p += __shfl_down(p, 4, 8);
    p += __shfl_down(p, 2, 8);
    p += __shfl_down(p, 1, 8);
    if (q == 0) s[node] = p * ds;
}

__global__ void k_gather1(const float* __restrict__ sv, const int* __restrict__ es,
                          const int* __restrict__ offsets, const float* __restrict__ dis,
                          const float* __restrict__ b3, float* __restrict__ out, int n) {
    int d = blockIdx.x * 256 + threadIdx.x;
    if (d >= n) return;
    float acc = sv[d];
    int s0 = offsets[d], s1 = offsets[d + 1];
    int ei = s0;
    for (; ei + 4 <= s1; ei += 4) {
        float v0 = sv[es[ei]], v1 = sv[es[ei + 1]];
        float v2 = sv[es[ei + 2]], v3 = sv[es[ei + 3]];
        acc += (v0 + v1) + (v2 + v3);
    }
    for (; ei < s1; ++ei) acc += sv[es[ei]];
    float z = dis[d] * acc + b3[0];
    out[d] = 1.0f / (1.0f + expf(-z));
}

// ================= launch =================

extern "C" void kernel_launch(void* const* d_in, const int* in_sizes, int n_in,
                              void* d_out, int out_size, void* d_ws, size_t ws_size,
                              hipStream_t stream) {
    const float* x  = (const float*)d_in[0];
    const int*   ei = (const int*)d_in[1];
    const float* W1 = (const float*)d_in[2];
    const float* b1 = (const float*)d_in[3];
    const float* W2 = (const float*)d_in[4];
    const float* b2 = (const float*)d_in[5];
    const float* W3 = (const float*)d_in[6];
    const float* b3 = (const float*)d_in[7];
    float* out = (float*)d_out;

    int n = out_size;             // 150000
    int e = in_sizes[1] / 2;      // 2400000
    const int* src = ei;
    const int* dst = ei + e;

    int nbuckets = (n + NPB - 1) / NPB;   // 586

    float* A        = (float*)d_ws;                 // n*32 f
    float* B        = A + (size_t)n * HID;          // n*32 f (aliases tmp during CSR build)
    float* dis      = B + (size_t)n * HID;          // n f
    float* Cs       = dis + n;                      // n f
    int*   offsets  = (int*)(Cs + n);               // n+1 i
    int*   es       = offsets + (n + 1);            // e i
    int*   bin_hist = es + e;                       // nbuckets i
    int*   bin_off  = bin_hist + nbuckets;          // nbuckets+1 i
    int*   bin_cur  = bin_off + (nbuckets + 1);     // nbuckets i
    unsigned* tmp   = (unsigned*)B;

    dim3 blk(256);
    int gN    = (n + 255) / 256;
    int gN8   = (n * 8 + 255) / 256;
    int g128  = (n + 127) / 128;       // 1172
    int gEb   = (e + EPB - 1) / EPB;   // 293

    // ---- CSR build ----
    hipMemsetAsync(bin_hist, 0, (size_t)nbuckets * sizeof(int), stream);
    k_bhist<<<gEb, dim3(BLK_E), 0, stream>>>(dst, bin_hist, e, nbuckets);
    k_bscan<<<1, 1024, 0, stream>>>(bin_hist, bin_off, bin_cur, offsets, nbuckets, n, e);
    k_bpart<<<gEb, dim3(BLK_E), 0, stream>>>(src, dst, bin_cur, tmp, e, nbuckets);
    k_bcsr <<<nbuckets, dim3(BLK_C), 0, stream>>>(tmp, bin_off, es, offsets, dis, n);

    // ---- layer 1 ----
    k_gemm1   <<<g128, blk, 0, stream>>>(x, W1, dis, A, n);
    k_gather32<<<gN8, blk, 0, stream>>>((const float4*)A, es, offsets, dis, b1, (float4*)B, n);

    // ---- layer 2 (+ fused layer-3 transform) ----
    k_gemm2       <<<g128, blk, 0, stream>>>(B, W2, dis, A, n);
    k_gather32_dot<<<gN8, blk, 0, stream>>>((const float4*)A, es, offsets, dis, b2, W3, Cs, n);

    // ---- layer 3 aggregation ----
    k_gather1<<<gN, blk, 0, stream>>>(Cs, es, offsets, dis, b3, out, n);
}

// Round 4
// 325.745 us; speedup vs baseline: 1.7776x; 1.0655x over previous
//
#include <hip/hip_runtime.h>
#include <math.h>

#define F_IN 128
#define HID  32

#define NPB   256      // nodes per bucket (dst >> 8)
#define MAXNB 1024     // max buckets supported by the one-block scan
#define EPB   8192     // edges per block in coarse passes (293 blocks @ 2.4M)
#define BLK_E 1024     // threads per block for coarse passes
#define BLK_C 512      // threads per block for k_bcsr

#define XPAD  132      // 128 + 4: 16B-aligned row stride, conflict-free b128 reads

__device__ __forceinline__ void fma4(float4& a, float s, const float4& w) {
    a.x = fmaf(s, w.x, a.x);
    a.y = fmaf(s, w.y, a.y);
    a.z = fmaf(s, w.z, a.z);
    a.w = fmaf(s, w.w, a.w);
}

// ================= binned CSR build =================
// Block-local binning gives the scatter its write locality (runs of ~14
// edges into tmp; es writes into a 16KB block-owned window). Direct
// atomic scatter (round 2) cost 64B/write = 155MB. int4 edge loads for
// MLP in the latency-bound passes (round-3: kept CSR build off top-5).

__global__ __launch_bounds__(BLK_E) void k_bhist(const int* __restrict__ dst,
                                                 int* __restrict__ bin_hist,
                                                 int e, int nbuckets) {
    __shared__ int h[MAXNB];
    int tid = threadIdx.x;
    for (int i = tid; i < nbuckets; i += BLK_E) h[i] = 0;
    __syncthreads();
    int base = blockIdx.x * EPB;
    if (base + EPB <= e) {
        const int4* d4 = (const int4*)(dst + base);
#pragma unroll
        for (int i = tid; i < EPB / 4; i += BLK_E) {
            int4 v = d4[i];
            atomicAdd(&h[v.x >> 8], 1);
            atomicAdd(&h[v.y >> 8], 1);
            atomicAdd(&h[v.z >> 8], 1);
            atomicAdd(&h[v.w >> 8], 1);
        }
    } else {
        int end = e;
        for (int i = base + tid; i < end; i += BLK_E)
            atomicAdd(&h[dst[i] >> 8], 1);
    }
    __syncthreads();
    for (int i = tid; i < nbuckets; i += BLK_E)
        if (h[i]) atomicAdd(&bin_hist[i], h[i]);
}

__global__ __launch_bounds__(1024) void k_bscan(const int* __restrict__ bin_hist,
                                                int* __restrict__ bin_off,
                                                int* __restrict__ bin_cur,
                                                int* __restrict__ offsets,
                                                int nbuckets, int n, int e) {
    __shared__ int sh[MAXNB];
    int t = threadIdx.x;
    int v = (t < nbuckets) ? bin_hist[t] : 0;
    sh[t] = v; __syncthreads();
    for (int off = 1; off < MAXNB; off <<= 1) {
        int a = (t >= off) ? sh[t - off] : 0;
        __syncthreads();
        sh[t] += a;
        __syncthreads();
    }
    int excl = sh[t] - v;
    if (t < nbuckets) { bin_off[t] = excl; bin_cur[t] = excl; }
    if (t == 0) { bin_off[nbuckets] = e; offsets[n] = e; }
}

__global__ __launch_bounds__(BLK_E) void k_bpart(const int* __restrict__ src,
                                                 const int* __restrict__ dst,
                                                 int* __restrict__ bin_cur,
                                                 unsigned* __restrict__ tmp,
                                                 int e, int nbuckets) {
    __shared__ int h[MAXNB];
    __shared__ int lc[MAXNB];
    int tid = threadIdx.x;
    for (int i = tid; i < nbuckets; i += BLK_E) h[i] = 0;
    __syncthreads();
    int base = blockIdx.x * EPB;
    bool full = (base + EPB <= e);
    if (full) {
        const int4* d4 = (const int4*)(dst + base);
#pragma unroll
        for (int i = tid; i < EPB / 4; i += BLK_E) {
            int4 v = d4[i];
            atomicAdd(&h[v.x >> 8], 1);
            atomicAdd(&h[v.y >> 8], 1);
            atomicAdd(&h[v.z >> 8], 1);
            atomicAdd(&h[v.w >> 8], 1);
        }
    } else {
        for (int i = base + tid; i < e; i += BLK_E)
            atomicAdd(&h[dst[i] >> 8], 1);
    }
    __syncthreads();
    for (int i = tid; i < nbuckets; i += BLK_E) {
        int c = h[i];
        h[i] = c ? atomicAdd(&bin_cur[i], c) : 0;
        lc[i] = 0;
    }
    __syncthreads();
    if (full) {
        const int4* s4 = (const int4*)(src + base);
        const int4* d4 = (const int4*)(dst + base);
#pragma unroll
        for (int i = tid; i < EPB / 4; i += BLK_E) {
            int4 sv = s4[i];
            int4 dv = d4[i];
            int b0 = dv.x >> 8; int r0 = atomicAdd(&lc[b0], 1);
            tmp[h[b0] + r0] = (unsigned)sv.x | ((unsigned)(dv.x & (NPB - 1)) << 18);
            int b1 = dv.y >> 8; int r1 = atomicAdd(&lc[b1], 1);
            tmp[h[b1] + r1] = (unsigned)sv.y | ((unsigned)(dv.y & (NPB - 1)) << 18);
            int b2 = dv.z >> 8; int r2 = atomicAdd(&lc[b2], 1);
            tmp[h[b2] + r2] = (unsigned)sv.z | ((unsigned)(dv.z & (NPB - 1)) << 18);
            int b3 = dv.w >> 8; int r3 = atomicAdd(&lc[b3], 1);
            tmp[h[b3] + r3] = (unsigned)sv.w | ((unsigned)(dv.w & (NPB - 1)) << 18);
        }
    } else {
        for (int i = base + tid; i < e; i += BLK_E) {
            int d = dst[i];
            int b = d >> 8;
            int r = atomicAdd(&lc[b], 1);
            tmp[h[b] + r] = (unsigned)src[i] | ((unsigned)(d & (NPB - 1)) << 18);
        }
    }
}

__global__ __launch_bounds__(BLK_C) void k_bcsr(const unsigned* __restrict__ tmp,
                                                const int* __restrict__ bin_off,
                                                int* __restrict__ es,
                                                int* __restrict__ offsets,
                                                float* __restrict__ dis, int n) {
    __shared__ int cnt[NPB];
    __shared__ int sh[NPB];
    __shared__ int cur[NPB];
    int b = blockIdx.x, t = threadIdx.x;
    if (t < NPB) cnt[t] = 0;
    __syncthreads();
    int s0 = bin_off[b], s1 = bin_off[b + 1];
    for (int i = s0 + t; i < s1; i += BLK_C)
        atomicAdd(&cnt[(tmp[i] >> 18) & (NPB - 1)], 1);
    __syncthreads();
    int v = (t < NPB) ? cnt[t] : 0;
    if (t < NPB) sh[t] = v;
    __syncthreads();
    for (int off = 1; off < NPB; off <<= 1) {
        int a = (t < NPB && t >= off) ? sh[t - off] : 0;
        __syncthreads();
        if (t < NPB) sh[t] += a;
        __syncthreads();
    }
    if (t < NPB) {
        int excl = sh[t] - v;
        int node = b * NPB + t;
        if (node < n) {
            offsets[node] = s0 + excl;
            dis[node] = rsqrtf((float)(v + 1));
        }
        cur[t] = excl;
    }
    __syncthreads();
    for (int i = s0 + t; i < s1; i += BLK_C) {
        unsigned w = tmp[i];
        int dl = (w >> 18) & (NPB - 1);
        int r = atomicAdd(&cur[dl], 1);
        es[s0 + r] = (int)(w & 0x3FFFFu);
    }
}

// ================= transforms =================

// k_gemm1: m=2 (64 nodes/block, 2344 blocks for TLP) with the x-tile
// BULK-STAGED into LDS. Round-3 evidence: per-iteration dependent global
// x loads were the latency bottleneck (VALUBusy 18%, m=4's halved W
// traffic didn't help). Staging = 8 independent coalesced float4 loads
// per thread (deep MLP, full 64B lines), compute reads from LDS.
// Row stride XPAD=132 floats: 16B-aligned and compute-read bank-quads
// 4*(r+ks)%32 are distinct across the 8 rows a wave touches.
__global__ __launch_bounds__(256) void k_gemm1(const float* __restrict__ x,
                                               const float* __restrict__ W,
                                               const float* __restrict__ dis,
                                               float* __restrict__ u, int n) {
    __shared__ float Ws[F_IN * HID];   // 16 KB
    __shared__ float Xs[64 * XPAD];    // 33 KB
    int tid = threadIdx.x;
    for (int i = tid; i < F_IN * HID; i += 256) Ws[i] = W[i];
    int node0 = blockIdx.x * 64;
#pragma unroll
    for (int it = 0; it < 8; ++it) {
        int c  = it * 256 + tid;       // 2048 chunks of 16B
        int r  = c >> 5;               // 32 chunks per row
        int c4 = c & 31;
        int gr = node0 + r;
        if (gr >= n) gr = n - 1;       // in-bounds junk; outputs guarded
        float4 v = *(const float4*)&x[(size_t)gr * F_IN + c4 * 4];
        *(float4*)&Xs[r * XPAD + c4 * 4] = v;
    }
    int cg = tid & 7, gq = tid >> 3;
    float4 acc[2];
    acc[0] = make_float4(0.f, 0.f, 0.f, 0.f);
    acc[1] = make_float4(0.f, 0.f, 0.f, 0.f);
    __syncthreads();
#pragma unroll 4
    for (int ks = 0; ks < 32; ++ks) {
        float4 xv[2];
        xv[0] = *(const float4*)&Xs[gq * XPAD + ks * 4];
        xv[1] = *(const float4*)&Xs[(gq + 32) * XPAD + ks * 4];
        float4 w0 = *(const float4*)&Ws[(ks * 4 + 0) * HID + cg * 4];
        float4 w1 = *(const float4*)&Ws[(ks * 4 + 1) * HID + cg * 4];
        float4 w2 = *(const float4*)&Ws[(ks * 4 + 2) * HID + cg * 4];
        float4 w3 = *(const float4*)&Ws[(ks * 4 + 3) * HID + cg * 4];
#pragma unroll
        for (int m = 0; m < 2; ++m) {
            fma4(acc[m], xv[m].x, w0);
            fma4(acc[m], xv[m].y, w1);
            fma4(acc[m], xv[m].z, w2);
            fma4(acc[m], xv[m].w, w3);
        }
    }
#pragma unroll
    for (int m = 0; m < 2; ++m) {
        int node = node0 + gq + 32 * m;
        if (node < n) {
            float ds = dis[node];
            float4 r;
            r.x = acc[m].x * ds; r.y = acc[m].y * ds;
            r.z = acc[m].z * ds; r.w = acc[m].w * ds;
            *(float4*)&u[(size_t)node * HID + cg * 4] = r;
        }
    }
}

// round-0 proven m=2 form (never in top-5; one variable at a time)
__global__ __launch_bounds__(256) void k_gemm2(const float* __restrict__ h,
                                               const float* __restrict__ W,
                                               const float* __restrict__ dis,
                                               float* __restrict__ u, int n) {
    __shared__ float Ws[HID * HID];
    int tid = threadIdx.x;
    for (int i = tid; i < HID * HID; i += 256) Ws[i] = W[i];
    int node0 = blockIdx.x * 64;
    int cg = tid & 7, gq = tid >> 3;
    int row[2];
#pragma unroll
    for (int m = 0; m < 2; ++m) {
        int node = node0 + gq + 32 * m;
        row[m] = (node < n) ? node : 0;
    }
    const float4* h4 = (const float4*)h;
    float4 acc[2];
#pragma unroll
    for (int m = 0; m < 2; ++m) acc[m] = make_float4(0.f, 0.f, 0.f, 0.f);
    __syncthreads();
#pragma unroll 4
    for (int ks = 0; ks < 8; ++ks) {
        float4 xv[2];
#pragma unroll
        for (int m = 0; m < 2; ++m) xv[m] = h4[(size_t)row[m] * 8 + ks];
        float4 w0 = *(const float4*)&Ws[(ks * 4 + 0) * HID + cg * 4];
        float4 w1 = *(const float4*)&Ws[(ks * 4 + 1) * HID + cg * 4];
        float4 w2 = *(const float4*)&Ws[(ks * 4 + 2) * HID + cg * 4];
        float4 w3 = *(const float4*)&Ws[(ks * 4 + 3) * HID + cg * 4];
#pragma unroll
        for (int m = 0; m < 2; ++m) {
            fma4(acc[m], xv[m].x, w0);
            fma4(acc[m], xv[m].y, w1);
            fma4(acc[m], xv[m].z, w2);
            fma4(acc[m], xv[m].w, w3);
        }
    }
#pragma unroll
    for (int m = 0; m < 2; ++m) {
        int node = node0 + gq + 32 * m;
        if (node < n) {
            float ds = dis[node];
            float4 r;
            r.x = acc[m].x * ds; r.y = acc[m].y * ds;
            r.z = acc[m].z * ds; r.w = acc[m].w * ds;
            *(float4*)&u[(size_t)node * HID + cg * 4] = r;
        }
    }
}

// ================= gather aggregation =================

__global__ __launch_bounds__(256) void k_gather32(const float4* __restrict__ u4,
                                                  const int* __restrict__ es,
                                                  const int* __restrict__ offsets,
                                                  const float* __restrict__ dis,
                                                  const float* __restrict__ b,
                                                  float4* __restrict__ h4, int n) {
    int t = blockIdx.x * 256 + threadIdx.x;
    int node = t >> 3, q = t & 7;
    if (node >= n) return;
    int s0 = offsets[node];
    int s1 = offsets[node + 1];
    float4 acc = u4[(size_t)node * 8 + q];   // self-loop
    int ei = s0;
    for (; ei + 4 <= s1; ei += 4) {
        int e0 = es[ei], e1 = es[ei + 1], e2 = es[ei + 2], e3 = es[ei + 3];
        float4 v0 = u4[(size_t)e0 * 8 + q];
        float4 v1 = u4[(size_t)e1 * 8 + q];
        float4 v2 = u4[(size_t)e2 * 8 + q];
        float4 v3 = u4[(size_t)e3 * 8 + q];
        acc.x += (v0.x + v1.x) + (v2.x + v3.x);
        acc.y += (v0.y + v1.y) + (v2.y + v3.y);
        acc.z += (v0.z + v1.z) + (v2.z + v3.z);
        acc.w += (v0.w + v1.w) + (v2.w + v3.w);
    }
    for (; ei < s1; ++ei) {
        int s = es[ei];
        float4 v = u4[(size_t)s * 8 + q];
        acc.x += v.x; acc.y += v.y; acc.z += v.z; acc.w += v.w;
    }
    float ds = dis[node];
    float4 r;
    r.x = fmaxf(fmaf(ds, acc.x, b[q * 4 + 0]), 0.0f);
    r.y = fmaxf(fmaf(ds, acc.y, b[q * 4 + 1]), 0.0f);
    r.z = fmaxf(fmaf(ds, acc.z, b[q * 4 + 2]), 0.0f);
    r.w = fmaxf(fmaf(ds, acc.w, b[q * 4 + 3]), 0.0f);
    h4[(size_t)node * 8 + q] = r;
}

__global__ __launch_bounds__(256) void k_gather32_dot(const float4* __restrict__ u4,
                                                      const int* __restrict__ es,
                                                      const int* __restrict__ offsets,
                                                      const float* __restrict__ dis,
                                                      const float* __restrict__ b,
                                                      const float* __restrict__ W3,
                                                      float* __restrict__ s, int n) {
    int t = blockIdx.x * 256 + threadIdx.x;
    int node = t >> 3, q = t & 7;
    if (node >= n) return;
    int s0 = offsets[node];
    int s1 = offsets[node + 1];
    float4 acc = u4[(size_t)node * 8 + q];
    int ei = s0;
    for (; ei + 4 <= s1; ei += 4) {
        int e0 = es[ei], e1 = es[ei + 1], e2 = es[ei + 2], e3 = es[ei + 3];
        float4 v0 = u4[(size_t)e0 * 8 + q];
        float4 v1 = u4[(size_t)e1 * 8 + q];
        float4 v2 = u4[(size_t)e2 * 8 + q];
        float4 v3 = u4[(size_t)e3 * 8 + q];
        acc.x += (v0.x + v1.x) + (v2.x + v3.x);
        acc.y += (v0.y + v1.y) + (v2.y + v3.y);
        acc.z += (v0.z + v1.z) + (v2.z + v3.z);
        acc.w += (v0.w + v1.w) + (v2.w + v3.w);
    }
    for (; ei < s1; ++ei) {
        int sc = es[ei];
        float4 v = u4[(size_t)sc * 8 + q];
        acc.x += v.x; acc.y += v.y; acc.z += v.z; acc.w += v.w;
    }
    float ds = dis[node];
    float4 r;
    r.x = fmaxf(fmaf(ds, acc.x, b[q * 4 + 0]), 0.0f);
    r.y = fmaxf(fmaf(ds, acc.y, b[q * 4 + 1]), 0.0f);
    r.z = fmaxf(fmaf(ds, acc.z, b[q * 4 + 2]), 0.0f);
    r.w = fmaxf(fmaf(ds, acc.w, b[q * 4 + 3]), 0.0f);
    float p = r.x * W3[q * 4 + 0] + r.y * W3[q * 4 + 1]
            + r.z * W3[q * 4 + 2] + r.w * W3[q * 4 + 3];
    p += __shfl_down(p, 4, 8);
    p += __shfl_down(p, 2, 8);
    p += __shfl_down(p, 1, 8);
    if (q == 0) s[node] = p * ds;
}

__global__ void k_gather1(const float* __restrict__ sv, const int* __restrict__ es,
                          const int* __restrict__ offsets, const float* __restrict__ dis,
                          const float* __restrict__ b3, float* __restrict__ out, int n) {
    int d = blockIdx.x * 256 + threadIdx.x;
    if (d >= n) return;
    float acc = sv[d];
    int s0 = offsets[d], s1 = offsets[d + 1];
    int ei = s0;
    for (; ei + 4 <= s1; ei += 4) {
        float v0 = sv[es[ei]], v1 = sv[es[ei + 1]];
        float v2 = sv[es[ei + 2]], v3 = sv[es[ei + 3]];
        acc += (v0 + v1) + (v2 + v3);
    }
    for (; ei < s1; ++ei) acc += sv[es[ei]];
    float z = dis[d] * acc + b3[0];
    out[d] = 1.0f / (1.0f + expf(-z));
}

// ================= launch =================

extern "C" void kernel_launch(void* const* d_in, const int* in_sizes, int n_in,
                              void* d_out, int out_size, void* d_ws, size_t ws_size,
                              hipStream_t stream) {
    const float* x  = (const float*)d_in[0];
    const int*   ei = (const int*)d_in[1];
    const float* W1 = (const float*)d_in[2];
    const float* b1 = (const float*)d_in[3];
    const float* W2 = (const float*)d_in[4];
    const float* b2 = (const float*)d_in[5];
    const float* W3 = (const float*)d_in[6];
    const float* b3 = (const float*)d_in[7];
    float* out = (float*)d_out;

    int n = out_size;             // 150000
    int e = in_sizes[1] / 2;      // 2400000
    const int* src = ei;
    const int* dst = ei + e;

    int nbuckets = (n + NPB - 1) / NPB;   // 586

    float* A        = (float*)d_ws;                 // n*32 f
    float* B        = A + (size_t)n * HID;          // n*32 f (aliases tmp during CSR build)
    float* dis      = B + (size_t)n * HID;          // n f
    float* Cs       = dis + n;                      // n f
    int*   offsets  = (int*)(Cs + n);               // n+1 i
    int*   es       = offsets + (n + 1);            // e i
    int*   bin_hist = es + e;                       // nbuckets i
    int*   bin_off  = bin_hist + nbuckets;          // nbuckets+1 i
    int*   bin_cur  = bin_off + (nbuckets + 1);     // nbuckets i
    unsigned* tmp   = (unsigned*)B;

    dim3 blk(256);
    int gN    = (n + 255) / 256;
    int gN8   = (n * 8 + 255) / 256;
    int g64   = (n + 63) / 64;         // 2344
    int gEb   = (e + EPB - 1) / EPB;   // 293

    // ---- CSR build ----
    hipMemsetAsync(bin_hist, 0, (size_t)nbuckets * sizeof(int), stream);
    k_bhist<<<gEb, dim3(BLK_E), 0, stream>>>(dst, bin_hist, e, nbuckets);
    k_bscan<<<1, 1024, 0, stream>>>(bin_hist, bin_off, bin_cur, offsets, nbuckets, n, e);
    k_bpart<<<gEb, dim3(BLK_E), 0, stream>>>(src, dst, bin_cur, tmp, e, nbuckets);
    k_bcsr <<<nbuckets, dim3(BLK_C), 0, stream>>>(tmp, bin_off, es, offsets, dis, n);

    // ---- layer 1 ----
    k_gemm1   <<<g64, blk, 0, stream>>>(x, W1, dis, A, n);
    k_gather32<<<gN8, blk, 0, stream>>>((const float4*)A, es, offsets, dis, b1, (float4*)B, n);

    // ---- layer 2 (+ fused layer-3 transform) ----
    k_gemm2       <<<g64, blk, 0, stream>>>(B, W2, dis, A, n);
    k_gather32_dot<<<gN8, blk, 0, stream>>>((const float4*)A, es, offsets, dis, b2, W3, Cs, n);

    // ---- layer 3 aggregation ----
    k_gather1<<<gN, blk, 0, stream>>>(Cs, es, offsets, dis, b3, out, n);
}

// Round 5
// 323.525 us; speedup vs baseline: 1.7898x; 1.0069x over previous
//
#include <hip/hip_runtime.h>
#include <math.h>

#define F_IN 128
#define HID  32

#define NPB   256      // nodes per bucket (dst >> 8)
#define MAXNB 1024     // max buckets supported by the one-block scan
#define EPB   8192     // edges per block in coarse passes (293 blocks @ 2.4M)
#define BLK_E 1024     // threads per block for coarse passes
#define BLK_C 512      // threads per block for k_bcsr

#define XPAD  132      // 128 + 4: 16B-aligned row stride, conflict-free b128 reads

__device__ __forceinline__ void fma4(float4& a, float s, const float4& w) {
    a.x = fmaf(s, w.x, a.x);
    a.y = fmaf(s, w.y, a.y);
    a.z = fmaf(s, w.z, a.z);
    a.w = fmaf(s, w.w, a.w);
}

__device__ __forceinline__ void add4(float4& a, const float4& v) {
    a.x += v.x; a.y += v.y; a.z += v.z; a.w += v.w;
}

// ================= binned CSR build =================
// Block-local binning gives the scatter its write locality (runs of ~14
// edges into tmp; es writes into a 16KB block-owned window). Direct
// atomic scatter (round 2) cost 64B/write = 155MB. int4 edge loads for
// MLP in the latency-bound passes (round-3: kept CSR build off top-5).

__global__ __launch_bounds__(BLK_E) void k_bhist(const int* __restrict__ dst,
                                                 int* __restrict__ bin_hist,
                                                 int e, int nbuckets) {
    __shared__ int h[MAXNB];
    int tid = threadIdx.x;
    for (int i = tid; i < nbuckets; i += BLK_E) h[i] = 0;
    __syncthreads();
    int base = blockIdx.x * EPB;
    if (base + EPB <= e) {
        const int4* d4 = (const int4*)(dst + base);
#pragma unroll
        for (int i = tid; i < EPB / 4; i += BLK_E) {
            int4 v = d4[i];
            atomicAdd(&h[v.x >> 8], 1);
            atomicAdd(&h[v.y >> 8], 1);
            atomicAdd(&h[v.z >> 8], 1);
            atomicAdd(&h[v.w >> 8], 1);
        }
    } else {
        int end = e;
        for (int i = base + tid; i < end; i += BLK_E)
            atomicAdd(&h[dst[i] >> 8], 1);
    }
    __syncthreads();
    for (int i = tid; i < nbuckets; i += BLK_E)
        if (h[i]) atomicAdd(&bin_hist[i], h[i]);
}

__global__ __launch_bounds__(1024) void k_bscan(const int* __restrict__ bin_hist,
                                                int* __restrict__ bin_off,
                                                int* __restrict__ bin_cur,
                                                int* __restrict__ offsets,
                                                int nbuckets, int n, int e) {
    __shared__ int sh[MAXNB];
    int t = threadIdx.x;
    int v = (t < nbuckets) ? bin_hist[t] : 0;
    sh[t] = v; __syncthreads();
    for (int off = 1; off < MAXNB; off <<= 1) {
        int a = (t >= off) ? sh[t - off] : 0;
        __syncthreads();
        sh[t] += a;
        __syncthreads();
    }
    int excl = sh[t] - v;
    if (t < nbuckets) { bin_off[t] = excl; bin_cur[t] = excl; }
    if (t == 0) { bin_off[nbuckets] = e; offsets[n] = e; }
}

__global__ __launch_bounds__(BLK_E) void k_bpart(const int* __restrict__ src,
                                                 const int* __restrict__ dst,
                                                 int* __restrict__ bin_cur,
                                                 unsigned* __restrict__ tmp,
                                                 int e, int nbuckets) {
    __shared__ int h[MAXNB];
    __shared__ int lc[MAXNB];
    int tid = threadIdx.x;
    for (int i = tid; i < nbuckets; i += BLK_E) h[i] = 0;
    __syncthreads();
    int base = blockIdx.x * EPB;
    bool full = (base + EPB <= e);
    if (full) {
        const int4* d4 = (const int4*)(dst + base);
#pragma unroll
        for (int i = tid; i < EPB / 4; i += BLK_E) {
            int4 v = d4[i];
            atomicAdd(&h[v.x >> 8], 1);
            atomicAdd(&h[v.y >> 8], 1);
            atomicAdd(&h[v.z >> 8], 1);
            atomicAdd(&h[v.w >> 8], 1);
        }
    } else {
        for (int i = base + tid; i < e; i += BLK_E)
            atomicAdd(&h[dst[i] >> 8], 1);
    }
    __syncthreads();
    for (int i = tid; i < nbuckets; i += BLK_E) {
        int c = h[i];
        h[i] = c ? atomicAdd(&bin_cur[i], c) : 0;
        lc[i] = 0;
    }
    __syncthreads();
    if (full) {
        const int4* s4 = (const int4*)(src + base);
        const int4* d4 = (const int4*)(dst + base);
#pragma unroll
        for (int i = tid; i < EPB / 4; i += BLK_E) {
            int4 sv = s4[i];
            int4 dv = d4[i];
            int b0 = dv.x >> 8; int r0 = atomicAdd(&lc[b0], 1);
            tmp[h[b0] + r0] = (unsigned)sv.x | ((unsigned)(dv.x & (NPB - 1)) << 18);
            int b1 = dv.y >> 8; int r1 = atomicAdd(&lc[b1], 1);
            tmp[h[b1] + r1] = (unsigned)sv.y | ((unsigned)(dv.y & (NPB - 1)) << 18);
            int b2 = dv.z >> 8; int r2 = atomicAdd(&lc[b2], 1);
            tmp[h[b2] + r2] = (unsigned)sv.z | ((unsigned)(dv.z & (NPB - 1)) << 18);
            int b3 = dv.w >> 8; int r3 = atomicAdd(&lc[b3], 1);
            tmp[h[b3] + r3] = (unsigned)sv.w | ((unsigned)(dv.w & (NPB - 1)) << 18);
        }
    } else {
        for (int i = base + tid; i < e; i += BLK_E) {
            int d = dst[i];
            int b = d >> 8;
            int r = atomicAdd(&lc[b], 1);
            tmp[h[b] + r] = (unsigned)src[i] | ((unsigned)(d & (NPB - 1)) << 18);
        }
    }
}

__global__ __launch_bounds__(BLK_C) void k_bcsr(const unsigned* __restrict__ tmp,
                                                const int* __restrict__ bin_off,
                                                int* __restrict__ es,
                                                int* __restrict__ offsets,
                                                float* __restrict__ dis, int n) {
    __shared__ int cnt[NPB];
    __shared__ int sh[NPB];
    __shared__ int cur[NPB];
    int b = blockIdx.x, t = threadIdx.x;
    if (t < NPB) cnt[t] = 0;
    __syncthreads();
    int s0 = bin_off[b], s1 = bin_off[b + 1];
    for (int i = s0 + t; i < s1; i += BLK_C)
        atomicAdd(&cnt[(tmp[i] >> 18) & (NPB - 1)], 1);
    __syncthreads();
    int v = (t < NPB) ? cnt[t] : 0;
    if (t < NPB) sh[t] = v;
    __syncthreads();
    for (int off = 1; off < NPB; off <<= 1) {
        int a = (t < NPB && t >= off) ? sh[t - off] : 0;
        __syncthreads();
        if (t < NPB) sh[t] += a;
        __syncthreads();
    }
    if (t < NPB) {
        int excl = sh[t] - v;
        int node = b * NPB + t;
        if (node < n) {
            offsets[node] = s0 + excl;
            dis[node] = rsqrtf((float)(v + 1));
        }
        cur[t] = excl;
    }
    __syncthreads();
    for (int i = s0 + t; i < s1; i += BLK_C) {
        unsigned w = tmp[i];
        int dl = (w >> 18) & (NPB - 1);
        int r = atomicAdd(&cur[dl], 1);
        es[s0 + r] = (int)(w & 0x3FFFFu);
    }
}

// ================= transforms =================

// k_gemm1: m=2 (64 nodes/block, 2344 blocks for TLP) with the x-tile
// BULK-STAGED into LDS (round-4: took gemm1 off the top-5).
__global__ __launch_bounds__(256) void k_gemm1(const float* __restrict__ x,
                                               const float* __restrict__ W,
                                               const float* __restrict__ dis,
                                               float* __restrict__ u, int n) {
    __shared__ float Ws[F_IN * HID];   // 16 KB
    __shared__ float Xs[64 * XPAD];    // 33 KB
    int tid = threadIdx.x;
    for (int i = tid; i < F_IN * HID; i += 256) Ws[i] = W[i];
    int node0 = blockIdx.x * 64;
#pragma unroll
    for (int it = 0; it < 8; ++it) {
        int c  = it * 256 + tid;       // 2048 chunks of 16B
        int r  = c >> 5;               // 32 chunks per row
        int c4 = c & 31;
        int gr = node0 + r;
        if (gr >= n) gr = n - 1;       // in-bounds junk; outputs guarded
        float4 v = *(const float4*)&x[(size_t)gr * F_IN + c4 * 4];
        *(float4*)&Xs[r * XPAD + c4 * 4] = v;
    }
    int cg = tid & 7, gq = tid >> 3;
    float4 acc[2];
    acc[0] = make_float4(0.f, 0.f, 0.f, 0.f);
    acc[1] = make_float4(0.f, 0.f, 0.f, 0.f);
    __syncthreads();
#pragma unroll 4
    for (int ks = 0; ks < 32; ++ks) {
        float4 xv[2];
        xv[0] = *(const float4*)&Xs[gq * XPAD + ks * 4];
        xv[1] = *(const float4*)&Xs[(gq + 32) * XPAD + ks * 4];
        float4 w0 = *(const float4*)&Ws[(ks * 4 + 0) * HID + cg * 4];
        float4 w1 = *(const float4*)&Ws[(ks * 4 + 1) * HID + cg * 4];
        float4 w2 = *(const float4*)&Ws[(ks * 4 + 2) * HID + cg * 4];
        float4 w3 = *(const float4*)&Ws[(ks * 4 + 3) * HID + cg * 4];
#pragma unroll
        for (int m = 0; m < 2; ++m) {
            fma4(acc[m], xv[m].x, w0);
            fma4(acc[m], xv[m].y, w1);
            fma4(acc[m], xv[m].z, w2);
            fma4(acc[m], xv[m].w, w3);
        }
    }
#pragma unroll
    for (int m = 0; m < 2; ++m) {
        int node = node0 + gq + 32 * m;
        if (node < n) {
            float ds = dis[node];
            float4 r;
            r.x = acc[m].x * ds; r.y = acc[m].y * ds;
            r.z = acc[m].z * ds; r.w = acc[m].w * ds;
            *(float4*)&u[(size_t)node * HID + cg * 4] = r;
        }
    }
}

// round-0 proven m=2 form (never in top-5)
__global__ __launch_bounds__(256) void k_gemm2(const float* __restrict__ h,
                                               const float* __restrict__ W,
                                               const float* __restrict__ dis,
                                               float* __restrict__ u, int n) {
    __shared__ float Ws[HID * HID];
    int tid = threadIdx.x;
    for (int i = tid; i < HID * HID; i += 256) Ws[i] = W[i];
    int node0 = blockIdx.x * 64;
    int cg = tid & 7, gq = tid >> 3;
    int row[2];
#pragma unroll
    for (int m = 0; m < 2; ++m) {
        int node = node0 + gq + 32 * m;
        row[m] = (node < n) ? node : 0;
    }
    const float4* h4 = (const float4*)h;
    float4 acc[2];
#pragma unroll
    for (int m = 0; m < 2; ++m) acc[m] = make_float4(0.f, 0.f, 0.f, 0.f);
    __syncthreads();
#pragma unroll 4
    for (int ks = 0; ks < 8; ++ks) {
        float4 xv[2];
#pragma unroll
        for (int m = 0; m < 2; ++m) xv[m] = h4[(size_t)row[m] * 8 + ks];
        float4 w0 = *(const float4*)&Ws[(ks * 4 + 0) * HID + cg * 4];
        float4 w1 = *(const float4*)&Ws[(ks * 4 + 1) * HID + cg * 4];
        float4 w2 = *(const float4*)&Ws[(ks * 4 + 2) * HID + cg * 4];
        float4 w3 = *(const float4*)&Ws[(ks * 4 + 3) * HID + cg * 4];
#pragma unroll
        for (int m = 0; m < 2; ++m) {
            fma4(acc[m], xv[m].x, w0);
            fma4(acc[m], xv[m].y, w1);
            fma4(acc[m], xv[m].z, w2);
            fma4(acc[m], xv[m].w, w3);
        }
    }
#pragma unroll
    for (int m = 0; m < 2; ++m) {
        int node = node0 + gq + 32 * m;
        if (node < n) {
            float ds = dis[node];
            float4 r;
            r.x = acc[m].x * ds; r.y = acc[m].y * ds;
            r.z = acc[m].z * ds; r.w = acc[m].w * ds;
            *(float4*)&u[(size_t)node * HID + cg * 4] = r;
        }
    }
}

// ================= gather aggregation =================
// Round-5: 8-wide unroll. The gather was latency-bound on the 2-level
// dependent chain (es -> u4), VALUBusy 11.6%, BW 55% of achievable.
// 8 independent es loads + 8 independent u4 gathers in flight per wait
// halves the serialized round trips per node (mean degree 16).

__global__ __launch_bounds__(256) void k_gather32(const float4* __restrict__ u4,
                                                  const int* __restrict__ es,
                                                  const int* __restrict__ offsets,
                                                  const float* __restrict__ dis,
                                                  const float* __restrict__ b,
                                                  float4* __restrict__ h4, int n) {
    int t = blockIdx.x * 256 + threadIdx.x;
    int node = t >> 3, q = t & 7;
    if (node >= n) return;
    int s0 = offsets[node];
    int s1 = offsets[node + 1];
    float4 acc = u4[(size_t)node * 8 + q];   // self-loop
    int ei = s0;
    for (; ei + 8 <= s1; ei += 8) {
        int e0 = es[ei], e1 = es[ei + 1], e2 = es[ei + 2], e3 = es[ei + 3];
        int e4 = es[ei + 4], e5 = es[ei + 5], e6 = es[ei + 6], e7 = es[ei + 7];
        float4 v0 = u4[(size_t)e0 * 8 + q];
        float4 v1 = u4[(size_t)e1 * 8 + q];
        float4 v2 = u4[(size_t)e2 * 8 + q];
        float4 v3 = u4[(size_t)e3 * 8 + q];
        float4 v4 = u4[(size_t)e4 * 8 + q];
        float4 v5 = u4[(size_t)e5 * 8 + q];
        float4 v6 = u4[(size_t)e6 * 8 + q];
        float4 v7 = u4[(size_t)e7 * 8 + q];
        acc.x += ((v0.x + v1.x) + (v2.x + v3.x)) + ((v4.x + v5.x) + (v6.x + v7.x));
        acc.y += ((v0.y + v1.y) + (v2.y + v3.y)) + ((v4.y + v5.y) + (v6.y + v7.y));
        acc.z += ((v0.z + v1.z) + (v2.z + v3.z)) + ((v4.z + v5.z) + (v6.z + v7.z));
        acc.w += ((v0.w + v1.w) + (v2.w + v3.w)) + ((v4.w + v5.w) + (v6.w + v7.w));
    }
    for (; ei + 4 <= s1; ei += 4) {
        int e0 = es[ei], e1 = es[ei + 1], e2 = es[ei + 2], e3 = es[ei + 3];
        float4 v0 = u4[(size_t)e0 * 8 + q];
        float4 v1 = u4[(size_t)e1 * 8 + q];
        float4 v2 = u4[(size_t)e2 * 8 + q];
        float4 v3 = u4[(size_t)e3 * 8 + q];
        acc.x += (v0.x + v1.x) + (v2.x + v3.x);
        acc.y += (v0.y + v1.y) + (v2.y + v3.y);
        acc.z += (v0.z + v1.z) + (v2.z + v3.z);
        acc.w += (v0.w + v1.w) + (v2.w + v3.w);
    }
    for (; ei < s1; ++ei) {
        int s = es[ei];
        float4 v = u4[(size_t)s * 8 + q];
        add4(acc, v);
    }
    float ds = dis[node];
    float4 r;
    r.x = fmaxf(fmaf(ds, acc.x, b[q * 4 + 0]), 0.0f);
    r.y = fmaxf(fmaf(ds, acc.y, b[q * 4 + 1]), 0.0f);
    r.z = fmaxf(fmaf(ds, acc.z, b[q * 4 + 2]), 0.0f);
    r.w = fmaxf(fmaf(ds, acc.w, b[q * 4 + 3]), 0.0f);
    h4[(size_t)node * 8 + q] = r;
}

__global__ __launch_bounds__(256) void k_gather32_dot(const float4* __restrict__ u4,
                                                      const int* __restrict__ es,
                                                      const int* __restrict__ offsets,
                                                      const float* __restrict__ dis,
                                                      const float* __restrict__ b,
                                                      const float* __restrict__ W3,
                                                      float* __restrict__ s, int n) {
    int t = blockIdx.x * 256 + threadIdx.x;
    int node = t >> 3, q = t & 7;
    if (node >= n) return;
    int s0 = offsets[node];
    int s1 = offsets[node + 1];
    float4 acc = u4[(size_t)node * 8 + q];
    int ei = s0;
    for (; ei + 8 <= s1; ei += 8) {
        int e0 = es[ei], e1 = es[ei + 1], e2 = es[ei + 2], e3 = es[ei + 3];
        int e4 = es[ei + 4], e5 = es[ei + 5], e6 = es[ei + 6], e7 = es[ei + 7];
        float4 v0 = u4[(size_t)e0 * 8 + q];
        float4 v1 = u4[(size_t)e1 * 8 + q];
        float4 v2 = u4[(size_t)e2 * 8 + q];
        float4 v3 = u4[(size_t)e3 * 8 + q];
        float4 v4 = u4[(size_t)e4 * 8 + q];
        float4 v5 = u4[(size_t)e5 * 8 + q];
        float4 v6 = u4[(size_t)e6 * 8 + q];
        float4 v7 = u4[(size_t)e7 * 8 + q];
        acc.x += ((v0.x + v1.x) + (v2.x + v3.x)) + ((v4.x + v5.x) + (v6.x + v7.x));
        acc.y += ((v0.y + v1.y) + (v2.y + v3.y)) + ((v4.y + v5.y) + (v6.y + v7.y));
        acc.z += ((v0.z + v1.z) + (v2.z + v3.z)) + ((v4.z + v5.z) + (v6.z + v7.z));
        acc.w += ((v0.w + v1.w) + (v2.w + v3.w)) + ((v4.w + v5.w) + (v6.w + v7.w));
    }
    for (; ei + 4 <= s1; ei += 4) {
        int e0 = es[ei], e1 = es[ei + 1], e2 = es[ei + 2], e3 = es[ei + 3];
        float4 v0 = u4[(size_t)e0 * 8 + q];
        float4 v1 = u4[(size_t)e1 * 8 + q];
        float4 v2 = u4[(size_t)e2 * 8 + q];
        float4 v3 = u4[(size_t)e3 * 8 + q];
        acc.x += (v0.x + v1.x) + (v2.x + v3.x);
        acc.y += (v0.y + v1.y) + (v2.y + v3.y);
        acc.z += (v0.z + v1.z) + (v2.z + v3.z);
        acc.w += (v0.w + v1.w) + (v2.w + v3.w);
    }
    for (; ei < s1; ++ei) {
        int sc = es[ei];
        float4 v = u4[(size_t)sc * 8 + q];
        add4(acc, v);
    }
    float ds = dis[node];
    float4 r;
    r.x = fmaxf(fmaf(ds, acc.x, b[q * 4 + 0]), 0.0f);
    r.y = fmaxf(fmaf(ds, acc.y, b[q * 4 + 1]), 0.0f);
    r.z = fmaxf(fmaf(ds, acc.z, b[q * 4 + 2]), 0.0f);
    r.w = fmaxf(fmaf(ds, acc.w, b[q * 4 + 3]), 0.0f);
    float p = r.x * W3[q * 4 + 0] + r.y * W3[q * 4 + 1]
            + r.z * W3[q * 4 + 2] + r.w * W3[q * 4 + 3];
    p += __shfl_down(p, 4, 8);
    p += __shfl_down(p, 2, 8);
    p += __shfl_down(p, 1, 8);
    if (q == 0) s[node] = p * ds;
}

__global__ void k_gather1(const float* __restrict__ sv, const int* __restrict__ es,
                          const int* __restrict__ offsets, const float* __restrict__ dis,
                          const float* __restrict__ b3, float* __restrict__ out, int n) {
    int d = blockIdx.x * 256 + threadIdx.x;
    if (d >= n) return;
    float acc = sv[d];
    int s0 = offsets[d], s1 = offsets[d + 1];
    int ei = s0;
    for (; ei + 4 <= s1; ei += 4) {
        float v0 = sv[es[ei]], v1 = sv[es[ei + 1]];
        float v2 = sv[es[ei + 2]], v3 = sv[es[ei + 3]];
        acc += (v0 + v1) + (v2 + v3);
    }
    for (; ei < s1; ++ei) acc += sv[es[ei]];
    float z = dis[d] * acc + b3[0];
    out[d] = 1.0f / (1.0f + expf(-z));
}

// ================= launch =================

extern "C" void kernel_launch(void* const* d_in, const int* in_sizes, int n_in,
                              void* d_out, int out_size, void* d_ws, size_t ws_size,
                              hipStream_t stream) {
    const float* x  = (const float*)d_in[0];
    const int*   ei = (const int*)d_in[1];
    const float* W1 = (const float*)d_in[2];
    const float* b1 = (const float*)d_in[3];
    const float* W2 = (const float*)d_in[4];
    const float* b2 = (const float*)d_in[5];
    const float* W3 = (const float*)d_in[6];
    const float* b3 = (const float*)d_in[7];
    float* out = (float*)d_out;

    int n = out_size;             // 150000
    int e = in_sizes[1] / 2;      // 2400000
    const int* src = ei;
    const int* dst = ei + e;

    int nbuckets = (n + NPB - 1) / NPB;   // 586

    float* A        = (float*)d_ws;                 // n*32 f
    float* B        = A + (size_t)n * HID;          // n*32 f (aliases tmp during CSR build)
    float* dis      = B + (size_t)n * HID;          // n f
    float* Cs       = dis + n;                      // n f
    int*   offsets  = (int*)(Cs + n);               // n+1 i
    int*   es       = offsets + (n + 1);            // e i
    int*   bin_hist = es + e;                       // nbuckets i
    int*   bin_off  = bin_hist + nbuckets;          // nbuckets+1 i
    int*   bin_cur  = bin_off + (nbuckets + 1);     // nbuckets i
    unsigned* tmp   = (unsigned*)B;

    dim3 blk(256);
    int gN    = (n + 255) / 256;
    int gN8   = (n * 8 + 255) / 256;
    int g64   = (n + 63) / 64;         // 2344
    int gEb   = (e + EPB - 1) / EPB;   // 293

    // ---- CSR build ----
    hipMemsetAsync(bin_hist, 0, (size_t)nbuckets * sizeof(int), stream);
    k_bhist<<<gEb, dim3(BLK_E), 0, stream>>>(dst, bin_hist, e, nbuckets);
    k_bscan<<<1, 1024, 0, stream>>>(bin_hist, bin_off, bin_cur, offsets, nbuckets, n, e);
    k_bpart<<<gEb, dim3(BLK_E), 0, stream>>>(src, dst, bin_cur, tmp, e, nbuckets);
    k_bcsr <<<nbuckets, dim3(BLK_C), 0, stream>>>(tmp, bin_off, es, offsets, dis, n);

    // ---- layer 1 ----
    k_gemm1   <<<g64, blk, 0, stream>>>(x, W1, dis, A, n);
    k_gather32<<<gN8, blk, 0, stream>>>((const float4*)A, es, offsets, dis, b1, (float4*)B, n);

    // ---- layer 2 (+ fused layer-3 transform) ----
    k_gemm2       <<<g64, blk, 0, stream>>>(B, W2, dis, A, n);
    k_gather32_dot<<<gN8, blk, 0, stream>>>((const float4*)A, es, offsets, dis, b2, W3, Cs, n);

    // ---- layer 3 aggregation ----
    k_gather1<<<gN, blk, 0, stream>>>(Cs, es, offsets, dis, b3, out, n);
}

// Round 7
// 315.277 us; speedup vs baseline: 1.8366x; 1.0262x over previous
//
#include <hip/hip_runtime.h>
#include <math.h>

#define F_IN 128
#define HID  32

#define NPB   256      // nodes per bucket (dst >> 8)
#define MAXNB 1024     // max buckets supported by the one-block scan
#define EPB   8192     // edges per block in coarse passes (293 blocks @ 2.4M)
#define BLK_E 1024     // threads per block for coarse passes
#define BLK_C 512      // threads per block for k_bcsr

#define XPAD  132      // 128 + 4: 16B-aligned row stride, conflict-free b128 reads

__device__ __forceinline__ void fma4(float4& a, float s, const float4& w) {
    a.x = fmaf(s, w.x, a.x);
    a.y = fmaf(s, w.y, a.y);
    a.z = fmaf(s, w.z, a.z);
    a.w = fmaf(s, w.w, a.w);
}

__device__ __forceinline__ void add4(float4& a, const float4& v) {
    a.x += v.x; a.y += v.y; a.z += v.z; a.w += v.w;
}

__device__ __forceinline__ float4 shx4(float4 v, int m) {
    float4 r;
    r.x = __shfl_xor(v.x, m);
    r.y = __shfl_xor(v.y, m);
    r.z = __shfl_xor(v.z, m);
    r.w = __shfl_xor(v.w, m);
    return r;
}

// ================= binned CSR build =================
// Block-local binning gives the scatter its write locality (runs of ~14
// edges into tmp; es writes into a 16KB block-owned window). Direct
// atomic scatter (round 2) cost 64B/write = 155MB. int4 edge loads for
// MLP. Round-6: bhist persists per-block histograms (hb) so bpart skips
// its redundant histogram pass (9.6MB dst re-read + 2.4M LDS atomics).

__global__ __launch_bounds__(BLK_E) void k_bhist(const int* __restrict__ dst,
                                                 int* __restrict__ bin_hist,
                                                 int* __restrict__ hb,
                                                 int e, int nbuckets) {
    __shared__ int h[MAXNB];
    int tid = threadIdx.x;
    for (int i = tid; i < nbuckets; i += BLK_E) h[i] = 0;
    __syncthreads();
    int base = blockIdx.x * EPB;
    if (base + EPB <= e) {
        const int4* d4 = (const int4*)(dst + base);
#pragma unroll
        for (int i = tid; i < EPB / 4; i += BLK_E) {
            int4 v = d4[i];
            atomicAdd(&h[v.x >> 8], 1);
            atomicAdd(&h[v.y >> 8], 1);
            atomicAdd(&h[v.z >> 8], 1);
            atomicAdd(&h[v.w >> 8], 1);
        }
    } else {
        int end = e;
        for (int i = base + tid; i < end; i += BLK_E)
            atomicAdd(&h[dst[i] >> 8], 1);
    }
    __syncthreads();
    size_t hbase = (size_t)blockIdx.x * nbuckets;
    for (int i = tid; i < nbuckets; i += BLK_E) {
        int c = h[i];
        if (c) atomicAdd(&bin_hist[i], c);
        hb[hbase + i] = c;
    }
}

__global__ __launch_bounds__(1024) void k_bscan(const int* __restrict__ bin_hist,
                                                int* __restrict__ bin_off,
                                                int* __restrict__ bin_cur,
                                                int* __restrict__ offsets,
                                                int nbuckets, int n, int e) {
    __shared__ int sh[MAXNB];
    int t = threadIdx.x;
    int v = (t < nbuckets) ? bin_hist[t] : 0;
    sh[t] = v; __syncthreads();
    for (int off = 1; off < MAXNB; off <<= 1) {
        int a = (t >= off) ? sh[t - off] : 0;
        __syncthreads();
        sh[t] += a;
        __syncthreads();
    }
    int excl = sh[t] - v;
    if (t < nbuckets) { bin_off[t] = excl; bin_cur[t] = excl; }
    if (t == 0) { bin_off[nbuckets] = e; offsets[n] = e; }
}

__global__ __launch_bounds__(BLK_E) void k_bpart(const int* __restrict__ src,
                                                 const int* __restrict__ dst,
                                                 int* __restrict__ bin_cur,
                                                 unsigned* __restrict__ tmp,
                                                 const int* __restrict__ hb,
                                                 int e, int nbuckets) {
    __shared__ int h[MAXNB];
    __shared__ int lc[MAXNB];
    int tid = threadIdx.x;
    size_t hbase = (size_t)blockIdx.x * nbuckets;
    // claim bin ranges from the persisted per-block histogram (no re-hist)
    for (int i = tid; i < nbuckets; i += BLK_E) {
        int c = hb[hbase + i];
        h[i] = c ? atomicAdd(&bin_cur[i], c) : 0;
        lc[i] = 0;
    }
    __syncthreads();
    int base = blockIdx.x * EPB;
    bool full = (base + EPB <= e);
    if (full) {
        const int4* s4 = (const int4*)(src + base);
        const int4* d4 = (const int4*)(dst + base);
#pragma unroll
        for (int i = tid; i < EPB / 4; i += BLK_E) {
            int4 sv = s4[i];
            int4 dv = d4[i];
            int b0 = dv.x >> 8; int r0 = atomicAdd(&lc[b0], 1);
            tmp[h[b0] + r0] = (unsigned)sv.x | ((unsigned)(dv.x & (NPB - 1)) << 18);
            int b1 = dv.y >> 8; int r1 = atomicAdd(&lc[b1], 1);
            tmp[h[b1] + r1] = (unsigned)sv.y | ((unsigned)(dv.y & (NPB - 1)) << 18);
            int b2 = dv.z >> 8; int r2 = atomicAdd(&lc[b2], 1);
            tmp[h[b2] + r2] = (unsigned)sv.z | ((unsigned)(dv.z & (NPB - 1)) << 18);
            int b3 = dv.w >> 8; int r3 = atomicAdd(&lc[b3], 1);
            tmp[h[b3] + r3] = (unsigned)sv.w | ((unsigned)(dv.w & (NPB - 1)) << 18);
        }
    } else {
        for (int i = base + tid; i < e; i += BLK_E) {
            int d = dst[i];
            int b = d >> 8;
            int r = atomicAdd(&lc[b], 1);
            tmp[h[b] + r] = (unsigned)src[i] | ((unsigned)(d & (NPB - 1)) << 18);
        }
    }
}

__global__ __launch_bounds__(BLK_C) void k_bcsr(const unsigned* __restrict__ tmp,
                                                const int* __restrict__ bin_off,
                                                int* __restrict__ es,
                                                int* __restrict__ offsets,
                                                float* __restrict__ dis, int n) {
    __shared__ int cnt[NPB];
    __shared__ int sh[NPB];
    __shared__ int cur[NPB];
    int b = blockIdx.x, t = threadIdx.x;
    if (t < NPB) cnt[t] = 0;
    __syncthreads();
    int s0 = bin_off[b], s1 = bin_off[b + 1];
    for (int i = s0 + t; i < s1; i += BLK_C)
        atomicAdd(&cnt[(tmp[i] >> 18) & (NPB - 1)], 1);
    __syncthreads();
    int v = (t < NPB) ? cnt[t] : 0;
    if (t < NPB) sh[t] = v;
    __syncthreads();
    for (int off = 1; off < NPB; off <<= 1) {
        int a = (t < NPB && t >= off) ? sh[t - off] : 0;
        __syncthreads();
        if (t < NPB) sh[t] += a;
        __syncthreads();
    }
    if (t < NPB) {
        int excl = sh[t] - v;
        int node = b * NPB + t;
        if (node < n) {
            offsets[node] = s0 + excl;
            dis[node] = rsqrtf((float)(v + 1));
        }
        cur[t] = excl;
    }
    __syncthreads();
    for (int i = s0 + t; i < s1; i += BLK_C) {
        unsigned w = tmp[i];
        int dl = (w >> 18) & (NPB - 1);
        int r = atomicAdd(&cur[dl], 1);
        es[s0 + r] = (int)(w & 0x3FFFFu);
    }
}

// ================= transforms =================

// k_gemm1: m=2 (64 nodes/block, 2344 blocks for TLP) with the x-tile
// BULK-STAGED into LDS (round-4: took gemm1 off the top-5).
__global__ __launch_bounds__(256) void k_gemm1(const float* __restrict__ x,
                                               const float* __restrict__ W,
                                               const float* __restrict__ dis,
                                               float* __restrict__ u, int n) {
    __shared__ float Ws[F_IN * HID];   // 16 KB
    __shared__ float Xs[64 * XPAD];    // 33 KB
    int tid = threadIdx.x;
    for (int i = tid; i < F_IN * HID; i += 256) Ws[i] = W[i];
    int node0 = blockIdx.x * 64;
#pragma unroll
    for (int it = 0; it < 8; ++it) {
        int c  = it * 256 + tid;       // 2048 chunks of 16B
        int r  = c >> 5;               // 32 chunks per row
        int c4 = c & 31;
        int gr = node0 + r;
        if (gr >= n) gr = n - 1;       // in-bounds junk; outputs guarded
        float4 v = *(const float4*)&x[(size_t)gr * F_IN + c4 * 4];
        *(float4*)&Xs[r * XPAD + c4 * 4] = v;
    }
    int cg = tid & 7, gq = tid >> 3;
    float4 acc[2];
    acc[0] = make_float4(0.f, 0.f, 0.f, 0.f);
    acc[1] = make_float4(0.f, 0.f, 0.f, 0.f);
    __syncthreads();
#pragma unroll 4
    for (int ks = 0; ks < 32; ++ks) {
        float4 xv[2];
        xv[0] = *(const float4*)&Xs[gq * XPAD + ks * 4];
        xv[1] = *(const float4*)&Xs[(gq + 32) * XPAD + ks * 4];
        float4 w0 = *(const float4*)&Ws[(ks * 4 + 0) * HID + cg * 4];
        float4 w1 = *(const float4*)&Ws[(ks * 4 + 1) * HID + cg * 4];
        float4 w2 = *(const float4*)&Ws[(ks * 4 + 2) * HID + cg * 4];
        float4 w3 = *(const float4*)&Ws[(ks * 4 + 3) * HID + cg * 4];
#pragma unroll
        for (int m = 0; m < 2; ++m) {
            fma4(acc[m], xv[m].x, w0);
            fma4(acc[m], xv[m].y, w1);
            fma4(acc[m], xv[m].z, w2);
            fma4(acc[m], xv[m].w, w3);
        }
    }
#pragma unroll
    for (int m = 0; m < 2; ++m) {
        int node = node0 + gq + 32 * m;
        if (node < n) {
            float ds = dis[node];
            float4 r;
            r.x = acc[m].x * ds; r.y = acc[m].y * ds;
            r.z = acc[m].z * ds; r.w = acc[m].w * ds;
            *(float4*)&u[(size_t)node * HID + cg * 4] = r;
        }
    }
}

// ================= gather aggregation =================
// Gather regime (rounds 4-5): BW-bound on the L2-miss path at ~3.5 TB/s;
// unroll depth beyond 8 gives nothing. So the layer-1 gather now absorbs
// gemm2: after computing the relu'd h-quad, butterfly-allgather the full
// 32-float h row across the 8-lane node group (7 float4 shfl_xor, all
// within the group), then lane q computes output quad q of h@W2 via
// conflict-free LDS reads. VALU/LDS cost hides under the gather's memory
// stalls (VALUBusy was 12%). Kills the gemm2 dispatch and its 38MB of
// B write+read.

__global__ __launch_bounds__(256) void k_gather32_g2(const float4* __restrict__ u4,
                                                     const int* __restrict__ es,
                                                     const int* __restrict__ offsets,
                                                     const float* __restrict__ dis,
                                                     const float* __restrict__ b,
                                                     const float* __restrict__ W2,
                                                     float* __restrict__ u2, int n) {
    __shared__ float Ws[HID * HID];   // 4 KB
    int tid = threadIdx.x;
    for (int i = tid; i < HID * HID; i += 256) Ws[i] = W2[i];
    __syncthreads();
    int t = blockIdx.x * 256 + tid;
    int node = t >> 3, q = t & 7;
    if (node >= n) return;
    int s0 = offsets[node];
    int s1 = offsets[node + 1];
    float4 acc = u4[(size_t)node * 8 + q];   // self-loop
    int ei = s0;
    for (; ei + 8 <= s1; ei += 8) {
        int e0 = es[ei], e1 = es[ei + 1], e2 = es[ei + 2], e3 = es[ei + 3];
        int e4 = es[ei + 4], e5 = es[ei + 5], e6 = es[ei + 6], e7 = es[ei + 7];
        float4 v0 = u4[(size_t)e0 * 8 + q];
        float4 v1 = u4[(size_t)e1 * 8 + q];
        float4 v2 = u4[(size_t)e2 * 8 + q];
        float4 v3 = u4[(size_t)e3 * 8 + q];
        float4 v4 = u4[(size_t)e4 * 8 + q];
        float4 v5 = u4[(size_t)e5 * 8 + q];
        float4 v6 = u4[(size_t)e6 * 8 + q];
        float4 v7 = u4[(size_t)e7 * 8 + q];
        acc.x += ((v0.x + v1.x) + (v2.x + v3.x)) + ((v4.x + v5.x) + (v6.x + v7.x));
        acc.y += ((v0.y + v1.y) + (v2.y + v3.y)) + ((v4.y + v5.y) + (v6.y + v7.y));
        acc.z += ((v0.z + v1.z) + (v2.z + v3.z)) + ((v4.z + v5.z) + (v6.z + v7.z));
        acc.w += ((v0.w + v1.w) + (v2.w + v3.w)) + ((v4.w + v5.w) + (v6.w + v7.w));
    }
    for (; ei + 4 <= s1; ei += 4) {
        int e0 = es[ei], e1 = es[ei + 1], e2 = es[ei + 2], e3 = es[ei + 3];
        float4 v0 = u4[(size_t)e0 * 8 + q];
        float4 v1 = u4[(size_t)e1 * 8 + q];
        float4 v2 = u4[(size_t)e2 * 8 + q];
        float4 v3 = u4[(size_t)e3 * 8 + q];
        acc.x += (v0.x + v1.x) + (v2.x + v3.x);
        acc.y += (v0.y + v1.y) + (v2.y + v3.y);
        acc.z += (v0.z + v1.z) + (v2.z + v3.z);
        acc.w += (v0.w + v1.w) + (v2.w + v3.w);
    }
    for (; ei < s1; ++ei) {
        int s = es[ei];
        float4 v = u4[(size_t)s * 8 + q];
        add4(acc, v);
    }
    float ds = dis[node];
    float4 r;   // h quad, k-range [q*4, q*4+4)
    r.x = fmaxf(fmaf(ds, acc.x, b[q * 4 + 0]), 0.0f);
    r.y = fmaxf(fmaf(ds, acc.y, b[q * 4 + 1]), 0.0f);
    r.z = fmaxf(fmaf(ds, acc.z, b[q * 4 + 2]), 0.0f);
    r.w = fmaxf(fmaf(ds, acc.w, b[q * 4 + 3]), 0.0f);

    // --- butterfly allgather: H0..H7 = full h row in every lane ---
    // (shuffles only cross q within the same node group; a node's 8
    // lanes are active together)
    float4 o1 = shx4(r, 1);
    float4 L0 = (q & 1) ? o1 : r;    // index (q&~1)+0
    float4 L1 = (q & 1) ? r  : o1;   // index (q&~1)+1
    float4 M0 = shx4(L0, 2);
    float4 M1 = shx4(L1, 2);
    float4 P0 = (q & 2) ? M0 : L0;   // (q&~3)+0
    float4 P1 = (q & 2) ? M1 : L1;   // +1
    float4 P2 = (q & 2) ? L0 : M0;   // +2
    float4 P3 = (q & 2) ? L1 : M1;   // +3
    float4 Q0 = shx4(P0, 4);
    float4 Q1 = shx4(P1, 4);
    float4 Q2 = shx4(P2, 4);
    float4 Q3 = shx4(P3, 4);
    float4 H0 = (q & 4) ? Q0 : P0;
    float4 H1 = (q & 4) ? Q1 : P1;
    float4 H2 = (q & 4) ? Q2 : P2;
    float4 H3 = (q & 4) ? Q3 : P3;
    float4 H4 = (q & 4) ? P0 : Q0;
    float4 H5 = (q & 4) ? P1 : Q1;
    float4 H6 = (q & 4) ? P2 : Q2;
    float4 H7 = (q & 4) ? P3 : Q3;

    // --- u2 quad q = (h @ W2)[q*4 .. q*4+3], scaled by ds ---
    float4 oacc = make_float4(0.f, 0.f, 0.f, 0.f);
#define G2_STEP(Hj, j) { \
    float4 w0 = *(const float4*)&Ws[((j) * 4 + 0) * HID + q * 4]; \
    float4 w1 = *(const float4*)&Ws[((j) * 4 + 1) * HID + q * 4]; \
    float4 w2 = *(const float4*)&Ws[((j) * 4 + 2) * HID + q * 4]; \
    float4 w3 = *(const float4*)&Ws[((j) * 4 + 3) * HID + q * 4]; \
    fma4(oacc, Hj.x, w0); fma4(oacc, Hj.y, w1); \
    fma4(oacc, Hj.z, w2); fma4(oacc, Hj.w, w3); }
    G2_STEP(H0, 0) G2_STEP(H1, 1) G2_STEP(H2, 2) G2_STEP(H3, 3)
    G2_STEP(H4, 4) G2_STEP(H5, 5) G2_STEP(H6, 6) G2_STEP(H7, 7)
#undef G2_STEP
    float4 w;
    w.x = oacc.x * ds; w.y = oacc.y * ds;
    w.z = oacc.z * ds; w.w = oacc.w * ds;
    *(float4*)&u2[(size_t)node * HID + q * 4] = w;
}

__global__ __launch_bounds__(256) void k_gather32_dot(const float4* __restrict__ u4,
                                                      const int* __restrict__ es,
                                                      const int* __restrict__ offsets,
                                                      const float* __restrict__ dis,
                                                      const float* __restrict__ b,
                                                      const float* __restrict__ W3,
                                                      float* __restrict__ s, int n) {
    int t = blockIdx.x * 256 + threadIdx.x;
    int node = t >> 3, q = t & 7;
    if (node >= n) return;
    int s0 = offsets[node];
    int s1 = offsets[node + 1];
    float4 acc = u4[(size_t)node * 8 + q];
    int ei = s0;
    for (; ei + 8 <= s1; ei += 8) {
        int e0 = es[ei], e1 = es[ei + 1], e2 = es[ei + 2], e3 = es[ei + 3];
        int e4 = es[ei + 4], e5 = es[ei + 5], e6 = es[ei + 6], e7 = es[ei + 7];
        float4 v0 = u4[(size_t)e0 * 8 + q];
        float4 v1 = u4[(size_t)e1 * 8 + q];
        float4 v2 = u4[(size_t)e2 * 8 + q];
        float4 v3 = u4[(size_t)e3 * 8 + q];
        float4 v4 = u4[(size_t)e4 * 8 + q];
        float4 v5 = u4[(size_t)e5 * 8 + q];
        float4 v6 = u4[(size_t)e6 * 8 + q];
        float4 v7 = u4[(size_t)e7 * 8 + q];
        acc.x += ((v0.x + v1.x) + (v2.x + v3.x)) + ((v4.x + v5.x) + (v6.x + v7.x));
        acc.y += ((v0.y + v1.y) + (v2.y + v3.y)) + ((v4.y + v5.y) + (v6.y + v7.y));
        acc.z += ((v0.z + v1.z) + (v2.z + v3.z)) + ((v4.z + v5.z) + (v6.z + v7.z));
        acc.w += ((v0.w + v1.w) + (v2.w + v3.w)) + ((v4.w + v5.w) + (v6.w + v7.w));
    }
    for (; ei + 4 <= s1; ei += 4) {
        int e0 = es[ei], e1 = es[ei + 1], e2 = es[ei + 2], e3 = es[ei + 3];
        float4 v0 = u4[(size_t)e0 * 8 + q];
        float4 v1 = u4[(size_t)e1 * 8 + q];
        float4 v2 = u4[(size_t)e2 * 8 + q];
        float4 v3 = u4[(size_t)e3 * 8 + q];
        acc.x += (v0.x + v1.x) + (v2.x + v3.x);
        acc.y += (v0.y + v1.y) + (v2.y + v3.y);
        acc.z += (v0.z + v1.z) + (v2.z + v3.z);
        acc.w += (v0.w + v1.w) + (v2.w + v3.w);
    }
    for (; ei < s1; ++ei) {
        int sc = es[ei];
        float4 v = u4[(size_t)sc * 8 + q];
        add4(acc, v);
    }
    float ds = dis[node];
    float4 r;
    r.x = fmaxf(fmaf(ds, acc.x, b[q * 4 + 0]), 0.0f);
    r.y = fmaxf(fmaf(ds, acc.y, b[q * 4 + 1]), 0.0f);
    r.z = fmaxf(fmaf(ds, acc.z, b[q * 4 + 2]), 0.0f);
    r.w = fmaxf(fmaf(ds, acc.w, b[q * 4 + 3]), 0.0f);
    float p = r.x * W3[q * 4 + 0] + r.y * W3[q * 4 + 1]
            + r.z * W3[q * 4 + 2] + r.w * W3[q * 4 + 3];
    p += __shfl_down(p, 4, 8);
    p += __shfl_down(p, 2, 8);
    p += __shfl_down(p, 1, 8);
    if (q == 0) s[node] = p * ds;
}

__global__ void k_gather1(const float* __restrict__ sv, const int* __restrict__ es,
                          const int* __restrict__ offsets, const float* __restrict__ dis,
                          const float* __restrict__ b3, float* __restrict__ out, int n) {
    int d = blockIdx.x * 256 + threadIdx.x;
    if (d >= n) return;
    float acc = sv[d];
    int s0 = offsets[d], s1 = offsets[d + 1];
    int ei = s0;
    for (; ei + 4 <= s1; ei += 4) {
        float v0 = sv[es[ei]], v1 = sv[es[ei + 1]];
        float v2 = sv[es[ei + 2]], v3 = sv[es[ei + 3]];
        acc += (v0 + v1) + (v2 + v3);
    }
    for (; ei < s1; ++ei) acc += sv[es[ei]];
    float z = dis[d] * acc + b3[0];
    out[d] = 1.0f / (1.0f + expf(-z));
}

// ================= launch =================

extern "C" void kernel_launch(void* const* d_in, const int* in_sizes, int n_in,
                              void* d_out, int out_size, void* d_ws, size_t ws_size,
                              hipStream_t stream) {
    const float* x  = (const float*)d_in[0];
    const int*   ei = (const int*)d_in[1];
    const float* W1 = (const float*)d_in[2];
    const float* b1 = (const float*)d_in[3];
    const float* W2 = (const float*)d_in[4];
    const float* b2 = (const float*)d_in[5];
    const float* W3 = (const float*)d_in[6];
    const float* b3 = (const float*)d_in[7];
    float* out = (float*)d_out;

    int n = out_size;             // 150000
    int e = in_sizes[1] / 2;      // 2400000
    const int* src = ei;
    const int* dst = ei + e;

    int nbuckets = (n + NPB - 1) / NPB;   // 586
    int gEb      = (e + EPB - 1) / EPB;   // 293

    float* A        = (float*)d_ws;                 // n*32 f
    float* B        = A + (size_t)n * HID;          // n*32 f (aliases tmp during CSR build)
    float* dis      = B + (size_t)n * HID;          // n f
    float* Cs       = dis + n;                      // n f
    int*   offsets  = (int*)(Cs + n);               // n+1 i
    int*   es       = offsets + (n + 1);            // e i
    int*   bin_hist = es + e;                       // nbuckets i
    int*   bin_off  = bin_hist + nbuckets;          // nbuckets+1 i
    int*   bin_cur  = bin_off + (nbuckets + 1);     // nbuckets i
    int*   hb       = bin_cur + nbuckets;           // gEb*nbuckets i (~687 KB)
    unsigned* tmp   = (unsigned*)B;

    dim3 blk(256);
    int gN    = (n + 255) / 256;
    int gN8   = (n * 8 + 255) / 256;
    int g64   = (n + 63) / 64;         // 2344

    // ---- CSR build ----
    hipMemsetAsync(bin_hist, 0, (size_t)nbuckets * sizeof(int), stream);
    k_bhist<<<gEb, dim3(BLK_E), 0, stream>>>(dst, bin_hist, hb, e, nbuckets);
    k_bscan<<<1, 1024, 0, stream>>>(bin_hist, bin_off, bin_cur, offsets, nbuckets, n, e);
    k_bpart<<<gEb, dim3(BLK_E), 0, stream>>>(src, dst, bin_cur, tmp, hb, e, nbuckets);
    k_bcsr <<<nbuckets, dim3(BLK_C), 0, stream>>>(tmp, bin_off, es, offsets, dis, n);

    // ---- layer 1 (+ fused layer-2 transform) ----
    k_gemm1      <<<g64, blk, 0, stream>>>(x, W1, dis, A, n);
    k_gather32_g2<<<gN8, blk, 0, stream>>>((const float4*)A, es, offsets, dis, b1, W2, B, n);

    // ---- layer 2 aggregation (+ fused layer-3 transform) ----
    k_gather32_dot<<<gN8, blk, 0, stream>>>((const float4*)B, es, offsets, dis, b2, W3, Cs, n);

    // ---- layer 3 aggregation ----
    k_gather1<<<gN, blk, 0, stream>>>(Cs, es, offsets, dis, b3, out, n);
}

// Round 8
// 300.801 us; speedup vs baseline: 1.9250x; 1.0481x over previous
//
#include <hip/hip_runtime.h>
#include <hip/hip_fp16.h>
#include <math.h>

#define F_IN 128
#define HID  32

#define NPB   256      // nodes per bucket (dst >> 8)
#define MAXNB 1024     // max buckets supported by the one-block scan
#define EPB   8192     // edges per block in coarse passes (293 blocks @ 2.4M)
#define BLK_E 1024     // threads per block for coarse passes
#define BLK_C 512      // threads per block for k_bcsr

#define XPAD  132      // 128 + 4: 16B-aligned row stride, conflict-free b128 reads

__device__ __forceinline__ void fma4(float4& a, float s, const float4& w) {
    a.x = fmaf(s, w.x, a.x);
    a.y = fmaf(s, w.y, a.y);
    a.z = fmaf(s, w.z, a.z);
    a.w = fmaf(s, w.w, a.w);
}

__device__ __forceinline__ void add4(float4& a, const float4& v) {
    a.x += v.x; a.y += v.y; a.z += v.z; a.w += v.w;
}

__device__ __forceinline__ float4 shx4(float4 v, int m) {
    float4 r;
    r.x = __shfl_xor(v.x, m);
    r.y = __shfl_xor(v.y, m);
    r.z = __shfl_xor(v.z, m);
    r.w = __shfl_xor(v.w, m);
    return r;
}

// fp16 quad load/store: 8B per lane, fp32 math everywhere else.
__device__ __forceinline__ float4 ldh4(const __half* p) {
    uint2 u = *(const uint2*)p;
    __half2 h0 = *(__half2*)&u.x;
    __half2 h1 = *(__half2*)&u.y;
    float2 f0 = __half22float2(h0);
    float2 f1 = __half22float2(h1);
    return make_float4(f0.x, f0.y, f1.x, f1.y);
}
__device__ __forceinline__ void sth4(__half* p, float4 v) {
    __half2 h0 = __floats2half2_rn(v.x, v.y);
    __half2 h1 = __floats2half2_rn(v.z, v.w);
    uint2 u;
    u.x = *(unsigned*)&h0;
    u.y = *(unsigned*)&h1;
    *(uint2*)p = u;
}

// ================= binned CSR build =================
// Block-local binning gives the scatter its write locality. int4 edge
// loads for MLP. bhist persists per-block histograms (hb) so bpart
// skips its redundant histogram pass.

__global__ __launch_bounds__(BLK_E) void k_bhist(const int* __restrict__ dst,
                                                 int* __restrict__ bin_hist,
                                                 int* __restrict__ hb,
                                                 int e, int nbuckets) {
    __shared__ int h[MAXNB];
    int tid = threadIdx.x;
    for (int i = tid; i < nbuckets; i += BLK_E) h[i] = 0;
    __syncthreads();
    int base = blockIdx.x * EPB;
    if (base + EPB <= e) {
        const int4* d4 = (const int4*)(dst + base);
#pragma unroll
        for (int i = tid; i < EPB / 4; i += BLK_E) {
            int4 v = d4[i];
            atomicAdd(&h[v.x >> 8], 1);
            atomicAdd(&h[v.y >> 8], 1);
            atomicAdd(&h[v.z >> 8], 1);
            atomicAdd(&h[v.w >> 8], 1);
        }
    } else {
        int end = e;
        for (int i = base + tid; i < end; i += BLK_E)
            atomicAdd(&h[dst[i] >> 8], 1);
    }
    __syncthreads();
    size_t hbase = (size_t)blockIdx.x * nbuckets;
    for (int i = tid; i < nbuckets; i += BLK_E) {
        int c = h[i];
        if (c) atomicAdd(&bin_hist[i], c);
        hb[hbase + i] = c;
    }
}

__global__ __launch_bounds__(1024) void k_bscan(const int* __restrict__ bin_hist,
                                                int* __restrict__ bin_off,
                                                int* __restrict__ bin_cur,
                                                int* __restrict__ offsets,
                                                int nbuckets, int n, int e) {
    __shared__ int sh[MAXNB];
    int t = threadIdx.x;
    int v = (t < nbuckets) ? bin_hist[t] : 0;
    sh[t] = v; __syncthreads();
    for (int off = 1; off < MAXNB; off <<= 1) {
        int a = (t >= off) ? sh[t - off] : 0;
        __syncthreads();
        sh[t] += a;
        __syncthreads();
    }
    int excl = sh[t] - v;
    if (t < nbuckets) { bin_off[t] = excl; bin_cur[t] = excl; }
    if (t == 0) { bin_off[nbuckets] = e; offsets[n] = e; }
}

__global__ __launch_bounds__(BLK_E) void k_bpart(const int* __restrict__ src,
                                                 const int* __restrict__ dst,
                                                 int* __restrict__ bin_cur,
                                                 unsigned* __restrict__ tmp,
                                                 const int* __restrict__ hb,
                                                 int e, int nbuckets) {
    __shared__ int h[MAXNB];
    __shared__ int lc[MAXNB];
    int tid = threadIdx.x;
    size_t hbase = (size_t)blockIdx.x * nbuckets;
    for (int i = tid; i < nbuckets; i += BLK_E) {
        int c = hb[hbase + i];
        h[i] = c ? atomicAdd(&bin_cur[i], c) : 0;
        lc[i] = 0;
    }
    __syncthreads();
    int base = blockIdx.x * EPB;
    bool full = (base + EPB <= e);
    if (full) {
        const int4* s4 = (const int4*)(src + base);
        const int4* d4 = (const int4*)(dst + base);
#pragma unroll
        for (int i = tid; i < EPB / 4; i += BLK_E) {
            int4 sv = s4[i];
            int4 dv = d4[i];
            int b0 = dv.x >> 8; int r0 = atomicAdd(&lc[b0], 1);
            tmp[h[b0] + r0] = (unsigned)sv.x | ((unsigned)(dv.x & (NPB - 1)) << 18);
            int b1 = dv.y >> 8; int r1 = atomicAdd(&lc[b1], 1);
            tmp[h[b1] + r1] = (unsigned)sv.y | ((unsigned)(dv.y & (NPB - 1)) << 18);
            int b2 = dv.z >> 8; int r2 = atomicAdd(&lc[b2], 1);
            tmp[h[b2] + r2] = (unsigned)sv.z | ((unsigned)(dv.z & (NPB - 1)) << 18);
            int b3 = dv.w >> 8; int r3 = atomicAdd(&lc[b3], 1);
            tmp[h[b3] + r3] = (unsigned)sv.w | ((unsigned)(dv.w & (NPB - 1)) << 18);
        }
    } else {
        for (int i = base + tid; i < e; i += BLK_E) {
            int d = dst[i];
            int b = d >> 8;
            int r = atomicAdd(&lc[b], 1);
            tmp[h[b] + r] = (unsigned)src[i] | ((unsigned)(d & (NPB - 1)) << 18);
        }
    }
}

__global__ __launch_bounds__(BLK_C) void k_bcsr(const unsigned* __restrict__ tmp,
                                                const int* __restrict__ bin_off,
                                                int* __restrict__ es,
                                                int* __restrict__ offsets,
                                                float* __restrict__ dis, int n) {
    __shared__ int cnt[NPB];
    __shared__ int sh[NPB];
    __shared__ int cur[NPB];
    int b = blockIdx.x, t = threadIdx.x;
    if (t < NPB) cnt[t] = 0;
    __syncthreads();
    int s0 = bin_off[b], s1 = bin_off[b + 1];
    for (int i = s0 + t; i < s1; i += BLK_C)
        atomicAdd(&cnt[(tmp[i] >> 18) & (NPB - 1)], 1);
    __syncthreads();
    int v = (t < NPB) ? cnt[t] : 0;
    if (t < NPB) sh[t] = v;
    __syncthreads();
    for (int off = 1; off < NPB; off <<= 1) {
        int a = (t < NPB && t >= off) ? sh[t - off] : 0;
        __syncthreads();
        if (t < NPB) sh[t] += a;
        __syncthreads();
    }
    if (t < NPB) {
        int excl = sh[t] - v;
        int node = b * NPB + t;
        if (node < n) {
            offsets[node] = s0 + excl;
            dis[node] = rsqrtf((float)(v + 1));
        }
        cur[t] = excl;
    }
    __syncthreads();
    for (int i = s0 + t; i < s1; i += BLK_C) {
        unsigned w = tmp[i];
        int dl = (w >> 18) & (NPB - 1);
        int r = atomicAdd(&cur[dl], 1);
        es[s0 + r] = (int)(w & 0x3FFFFu);
    }
}

// ================= transforms =================

// k_gemm1: x-tile bulk-staged in LDS (round 4); output now fp16
// (round 8: halves per-edge gather lines — MSHR-bound regime).
__global__ __launch_bounds__(256) void k_gemm1(const float* __restrict__ x,
                                               const float* __restrict__ W,
                                               const float* __restrict__ dis,
                                               __half* __restrict__ u, int n) {
    __shared__ float Ws[F_IN * HID];   // 16 KB
    __shared__ float Xs[64 * XPAD];    // 33 KB
    int tid = threadIdx.x;
    for (int i = tid; i < F_IN * HID; i += 256) Ws[i] = W[i];
    int node0 = blockIdx.x * 64;
#pragma unroll
    for (int it = 0; it < 8; ++it) {
        int c  = it * 256 + tid;       // 2048 chunks of 16B
        int r  = c >> 5;               // 32 chunks per row
        int c4 = c & 31;
        int gr = node0 + r;
        if (gr >= n) gr = n - 1;       // in-bounds junk; outputs guarded
        float4 v = *(const float4*)&x[(size_t)gr * F_IN + c4 * 4];
        *(float4*)&Xs[r * XPAD + c4 * 4] = v;
    }
    int cg = tid & 7, gq = tid >> 3;
    float4 acc[2];
    acc[0] = make_float4(0.f, 0.f, 0.f, 0.f);
    acc[1] = make_float4(0.f, 0.f, 0.f, 0.f);
    __syncthreads();
#pragma unroll 4
    for (int ks = 0; ks < 32; ++ks) {
        float4 xv[2];
        xv[0] = *(const float4*)&Xs[gq * XPAD + ks * 4];
        xv[1] = *(const float4*)&Xs[(gq + 32) * XPAD + ks * 4];
        float4 w0 = *(const float4*)&Ws[(ks * 4 + 0) * HID + cg * 4];
        float4 w1 = *(const float4*)&Ws[(ks * 4 + 1) * HID + cg * 4];
        float4 w2 = *(const float4*)&Ws[(ks * 4 + 2) * HID + cg * 4];
        float4 w3 = *(const float4*)&Ws[(ks * 4 + 3) * HID + cg * 4];
#pragma unroll
        for (int m = 0; m < 2; ++m) {
            fma4(acc[m], xv[m].x, w0);
            fma4(acc[m], xv[m].y, w1);
            fma4(acc[m], xv[m].z, w2);
            fma4(acc[m], xv[m].w, w3);
        }
    }
#pragma unroll
    for (int m = 0; m < 2; ++m) {
        int node = node0 + gq + 32 * m;
        if (node < n) {
            float ds = dis[node];
            float4 r;
            r.x = acc[m].x * ds; r.y = acc[m].y * ds;
            r.z = acc[m].z * ds; r.w = acc[m].w * ds;
            sth4(&u[(size_t)node * HID + cg * 4], r);
        }
    }
}

// ================= gather aggregation =================
// Regime (rounds 5/7): neither HBM (3.1 of 6.3 TB/s) nor VALU (20%) nor
// L2 saturated, unroll-depth null => per-CU outstanding-miss (MSHR)
// bound. fp16 node rows: 64B/edge = ONE line instead of two — halves
// the binding resource. Accumulation stays fp32. gemm2 fused in via
// 8-lane butterfly allgather + LDS W2 matmul (round 7: net +5us).

__global__ __launch_bounds__(256) void k_gather32_g2(const __half* __restrict__ uh,
                                                     const int* __restrict__ es,
                                                     const int* __restrict__ offsets,
                                                     const float* __restrict__ dis,
                                                     const float* __restrict__ b,
                                                     const float* __restrict__ W2,
                                                     __half* __restrict__ u2, int n) {
    __shared__ float Ws[HID * HID];   // 4 KB
    int tid = threadIdx.x;
    for (int i = tid; i < HID * HID; i += 256) Ws[i] = W2[i];
    __syncthreads();
    int t = blockIdx.x * 256 + tid;
    int node = t >> 3, q = t & 7;
    if (node >= n) return;
    int s0 = offsets[node];
    int s1 = offsets[node + 1];
    float4 acc = ldh4(&uh[(size_t)node * HID + q * 4]);   // self-loop
    int ei = s0;
    for (; ei + 8 <= s1; ei += 8) {
        int e0 = es[ei], e1 = es[ei + 1], e2 = es[ei + 2], e3 = es[ei + 3];
        int e4 = es[ei + 4], e5 = es[ei + 5], e6 = es[ei + 6], e7 = es[ei + 7];
        float4 v0 = ldh4(&uh[(size_t)e0 * HID + q * 4]);
        float4 v1 = ldh4(&uh[(size_t)e1 * HID + q * 4]);
        float4 v2 = ldh4(&uh[(size_t)e2 * HID + q * 4]);
        float4 v3 = ldh4(&uh[(size_t)e3 * HID + q * 4]);
        float4 v4 = ldh4(&uh[(size_t)e4 * HID + q * 4]);
        float4 v5 = ldh4(&uh[(size_t)e5 * HID + q * 4]);
        float4 v6 = ldh4(&uh[(size_t)e6 * HID + q * 4]);
        float4 v7 = ldh4(&uh[(size_t)e7 * HID + q * 4]);
        acc.x += ((v0.x + v1.x) + (v2.x + v3.x)) + ((v4.x + v5.x) + (v6.x + v7.x));
        acc.y += ((v0.y + v1.y) + (v2.y + v3.y)) + ((v4.y + v5.y) + (v6.y + v7.y));
        acc.z += ((v0.z + v1.z) + (v2.z + v3.z)) + ((v4.z + v5.z) + (v6.z + v7.z));
        acc.w += ((v0.w + v1.w) + (v2.w + v3.w)) + ((v4.w + v5.w) + (v6.w + v7.w));
    }
    for (; ei + 4 <= s1; ei += 4) {
        int e0 = es[ei], e1 = es[ei + 1], e2 = es[ei + 2], e3 = es[ei + 3];
        float4 v0 = ldh4(&uh[(size_t)e0 * HID + q * 4]);
        float4 v1 = ldh4(&uh[(size_t)e1 * HID + q * 4]);
        float4 v2 = ldh4(&uh[(size_t)e2 * HID + q * 4]);
        float4 v3 = ldh4(&uh[(size_t)e3 * HID + q * 4]);
        acc.x += (v0.x + v1.x) + (v2.x + v3.x);
        acc.y += (v0.y + v1.y) + (v2.y + v3.y);
        acc.z += (v0.z + v1.z) + (v2.z + v3.z);
        acc.w += (v0.w + v1.w) + (v2.w + v3.w);
    }
    for (; ei < s1; ++ei) {
        int s = es[ei];
        float4 v = ldh4(&uh[(size_t)s * HID + q * 4]);
        add4(acc, v);
    }
    float ds = dis[node];
    float4 r;   // h quad, k-range [q*4, q*4+4)
    r.x = fmaxf(fmaf(ds, acc.x, b[q * 4 + 0]), 0.0f);
    r.y = fmaxf(fmaf(ds, acc.y, b[q * 4 + 1]), 0.0f);
    r.z = fmaxf(fmaf(ds, acc.z, b[q * 4 + 2]), 0.0f);
    r.w = fmaxf(fmaf(ds, acc.w, b[q * 4 + 3]), 0.0f);

    // --- butterfly allgather: H0..H7 = full h row in every lane ---
    float4 o1 = shx4(r, 1);
    float4 L0 = (q & 1) ? o1 : r;
    float4 L1 = (q & 1) ? r  : o1;
    float4 M0 = shx4(L0, 2);
    float4 M1 = shx4(L1, 2);
    float4 P0 = (q & 2) ? M0 : L0;
    float4 P1 = (q & 2) ? M1 : L1;
    float4 P2 = (q & 2) ? L0 : M0;
    float4 P3 = (q & 2) ? L1 : M1;
    float4 Q0 = shx4(P0, 4);
    float4 Q1 = shx4(P1, 4);
    float4 Q2 = shx4(P2, 4);
    float4 Q3 = shx4(P3, 4);
    float4 H0 = (q & 4) ? Q0 : P0;
    float4 H1 = (q & 4) ? Q1 : P1;
    float4 H2 = (q & 4) ? Q2 : P2;
    float4 H3 = (q & 4) ? Q3 : P3;
    float4 H4 = (q & 4) ? P0 : Q0;
    float4 H5 = (q & 4) ? P1 : Q1;
    float4 H6 = (q & 4) ? P2 : Q2;
    float4 H7 = (q & 4) ? P3 : Q3;

    // --- u2 quad q = (h @ W2)[q*4 .. q*4+3], scaled by ds ---
    float4 oacc = make_float4(0.f, 0.f, 0.f, 0.f);
#define G2_STEP(Hj, j) { \
    float4 w0 = *(const float4*)&Ws[((j) * 4 + 0) * HID + q * 4]; \
    float4 w1 = *(const float4*)&Ws[((j) * 4 + 1) * HID + q * 4]; \
    float4 w2 = *(const float4*)&Ws[((j) * 4 + 2) * HID + q * 4]; \
    float4 w3 = *(const float4*)&Ws[((j) * 4 + 3) * HID + q * 4]; \
    fma4(oacc, Hj.x, w0); fma4(oacc, Hj.y, w1); \
    fma4(oacc, Hj.z, w2); fma4(oacc, Hj.w, w3); }
    G2_STEP(H0, 0) G2_STEP(H1, 1) G2_STEP(H2, 2) G2_STEP(H3, 3)
    G2_STEP(H4, 4) G2_STEP(H5, 5) G2_STEP(H6, 6) G2_STEP(H7, 7)
#undef G2_STEP
    float4 w;
    w.x = oacc.x * ds; w.y = oacc.y * ds;
    w.z = oacc.z * ds; w.w = oacc.w * ds;
    sth4(&u2[(size_t)node * HID + q * 4], w);
}

__global__ __launch_bounds__(256) void k_gather32_dot(const __half* __restrict__ uh,
                                                      const int* __restrict__ es,
                                                      const int* __restrict__ offsets,
                                                      const float* __restrict__ dis,
                                                      const float* __restrict__ b,
                                                      const float* __restrict__ W3,
                                                      float* __restrict__ s, int n) {
    int t = blockIdx.x * 256 + threadIdx.x;
    int node = t >> 3, q = t & 7;
    if (node >= n) return;
    int s0 = offsets[node];
    int s1 = offsets[node + 1];
    float4 acc = ldh4(&uh[(size_t)node * HID + q * 4]);
    int ei = s0;
    for (; ei + 8 <= s1; ei += 8) {
        int e0 = es[ei], e1 = es[ei + 1], e2 = es[ei + 2], e3 = es[ei + 3];
        int e4 = es[ei + 4], e5 = es[ei + 5], e6 = es[ei + 6], e7 = es[ei + 7];
        float4 v0 = ldh4(&uh[(size_t)e0 * HID + q * 4]);
        float4 v1 = ldh4(&uh[(size_t)e1 * HID + q * 4]);
        float4 v2 = ldh4(&uh[(size_t)e2 * HID + q * 4]);
        float4 v3 = ldh4(&uh[(size_t)e3 * HID + q * 4]);
        float4 v4 = ldh4(&uh[(size_t)e4 * HID + q * 4]);
        float4 v5 = ldh4(&uh[(size_t)e5 * HID + q * 4]);
        float4 v6 = ldh4(&uh[(size_t)e6 * HID + q * 4]);
        float4 v7 = ldh4(&uh[(size_t)e7 * HID + q * 4]);
        acc.x += ((v0.x + v1.x) + (v2.x + v3.x)) + ((v4.x + v5.x) + (v6.x + v7.x));
        acc.y += ((v0.y + v1.y) + (v2.y + v3.y)) + ((v4.y + v5.y) + (v6.y + v7.y));
        acc.z += ((v0.z + v1.z) + (v2.z + v3.z)) + ((v4.z + v5.z) + (v6.z + v7.z));
        acc.w += ((v0.w + v1.w) + (v2.w + v3.w)) + ((v4.w + v5.w) + (v6.w + v7.w));
    }
    for (; ei + 4 <= s1; ei += 4) {
        int e0 = es[ei], e1 = es[ei + 1], e2 = es[ei + 2], e3 = es[ei + 3];
        float4 v0 = ldh4(&uh[(size_t)e0 * HID + q * 4]);
        float4 v1 = ldh4(&uh[(size_t)e1 * HID + q * 4]);
        float4 v2 = ldh4(&uh[(size_t)e2 * HID + q * 4]);
        float4 v3 = ldh4(&uh[(size_t)e3 * HID + q * 4]);
        acc.x += (v0.x + v1.x) + (v2.x + v3.x);
        acc.y += (v0.y + v1.y) + (v2.y + v3.y);
        acc.z += (v0.z + v1.z) + (v2.z + v3.z);
        acc.w += (v0.w + v1.w) + (v2.w + v3.w);
    }
    for (; ei < s1; ++ei) {
        int sc = es[ei];
        float4 v = ldh4(&uh[(size_t)sc * HID + q * 4]);
        add4(acc, v);
    }
    float ds = dis[node];
    float4 r;
    r.x = fmaxf(fmaf(ds, acc.x, b[q * 4 + 0]), 0.0f);
    r.y = fmaxf(fmaf(ds, acc.y, b[q * 4 + 1]), 0.0f);
    r.z = fmaxf(fmaf(ds, acc.z, b[q * 4 + 2]), 0.0f);
    r.w = fmaxf(fmaf(ds, acc.w, b[q * 4 + 3]), 0.0f);
    float p = r.x * W3[q * 4 + 0] + r.y * W3[q * 4 + 1]
            + r.z * W3[q * 4 + 2] + r.w * W3[q * 4 + 3];
    p += __shfl_down(p, 4, 8);
    p += __shfl_down(p, 2, 8);
    p += __shfl_down(p, 1, 8);
    if (q == 0) s[node] = p * ds;
}

__global__ void k_gather1(const float* __restrict__ sv, const int* __restrict__ es,
                          const int* __restrict__ offsets, const float* __restrict__ dis,
                          const float* __restrict__ b3, float* __restrict__ out, int n) {
    int d = blockIdx.x * 256 + threadIdx.x;
    if (d >= n) return;
    float acc = sv[d];
    int s0 = offsets[d], s1 = offsets[d + 1];
    int ei = s0;
    for (; ei + 4 <= s1; ei += 4) {
        float v0 = sv[es[ei]], v1 = sv[es[ei + 1]];
        float v2 = sv[es[ei + 2]], v3 = sv[es[ei + 3]];
        acc += (v0 + v1) + (v2 + v3);
    }
    for (; ei < s1; ++ei) acc += sv[es[ei]];
    float z = dis[d] * acc + b3[0];
    out[d] = 1.0f / (1.0f + expf(-z));
}

// ================= launch =================

extern "C" void kernel_launch(void* const* d_in, const int* in_sizes, int n_in,
                              void* d_out, int out_size, void* d_ws, size_t ws_size,
                              hipStream_t stream) {
    const float* x  = (const float*)d_in[0];
    const int*   ei = (const int*)d_in[1];
    const float* W1 = (const float*)d_in[2];
    const float* b1 = (const float*)d_in[3];
    const float* W2 = (const float*)d_in[4];
    const float* b2 = (const float*)d_in[5];
    const float* W3 = (const float*)d_in[6];
    const float* b3 = (const float*)d_in[7];
    float* out = (float*)d_out;

    int n = out_size;             // 150000
    int e = in_sizes[1] / 2;      // 2400000
    const int* src = ei;
    const int* dst = ei + e;

    int nbuckets = (n + NPB - 1) / NPB;   // 586
    int gEb      = (e + EPB - 1) / EPB;   // 293

    __half* A       = (__half*)d_ws;                // n*32 halfs (9.6MB)
    __half* B       = A + (size_t)n * HID;          // n*32 halfs (9.6MB; aliases tmp)
    float* dis      = (float*)(B + (size_t)n * HID);// n f
    float* Cs       = dis + n;                      // n f
    int*   offsets  = (int*)(Cs + n);               // n+1 i
    int*   es       = offsets + (n + 1);            // e i
    int*   bin_hist = es + e;                       // nbuckets i
    int*   bin_off  = bin_hist + nbuckets;          // nbuckets+1 i
    int*   bin_cur  = bin_off + (nbuckets + 1);     // nbuckets i
    int*   hb       = bin_cur + nbuckets;           // gEb*nbuckets i (~687 KB)
    unsigned* tmp   = (unsigned*)B;                 // e u32 (9.6MB) == B size

    dim3 blk(256);
    int gN    = (n + 255) / 256;
    int gN8   = (n * 8 + 255) / 256;
    int g64   = (n + 63) / 64;         // 2344

    // ---- CSR build ----
    hipMemsetAsync(bin_hist, 0, (size_t)nbuckets * sizeof(int), stream);
    k_bhist<<<gEb, dim3(BLK_E), 0, stream>>>(dst, bin_hist, hb, e, nbuckets);
    k_bscan<<<1, 1024, 0, stream>>>(bin_hist, bin_off, bin_cur, offsets, nbuckets, n, e);
    k_bpart<<<gEb, dim3(BLK_E), 0, stream>>>(src, dst, bin_cur, tmp, hb, e, nbuckets);
    k_bcsr <<<nbuckets, dim3(BLK_C), 0, stream>>>(tmp, bin_off, es, offsets, dis, n);

    // ---- layer 1 (+ fused layer-2 transform) ----
    k_gemm1      <<<g64, blk, 0, stream>>>(x, W1, dis, A, n);
    k_gather32_g2<<<gN8, blk, 0, stream>>>(A, es, offsets, dis, b1, W2, B, n);

    // ---- layer 2 aggregation (+ fused layer-3 transform) ----
    k_gather32_dot<<<gN8, blk, 0, stream>>>(B, es, offsets, dis, b2, W3, Cs, n);

    // ---- layer 3 aggregation ----
    k_gather1<<<gN, blk, 0, stream>>>(Cs, es, offsets, dis, b3, out, n);
}